// Round 5
// baseline (75.261 us; speedup 1.0000x reference)
//
#include <hip/hip_runtime.h>

#define LEAKY(x) ((x) > 0.0f ? (x) : 0.01f * (x))

// ws float2 layout (consts only): ME[16] | U0c[64] | U1t[256] | GP[768]
// float offsets:
#define ME_F   0
#define U0C_F  32
#define U1T_F  160
#define GP_F   672

__device__ __forceinline__ float2 cmul(float2 a, float2 b) {
  return make_float2(fmaf(a.x, b.x, -a.y * b.y), fmaf(a.x, b.y, a.y * b.x));
}
__device__ __forceinline__ float2 cmulc(float2 a, float2 b) {  // conj(a)*b
  return make_float2(fmaf(a.x, b.x, a.y * b.y), fmaf(a.x, b.y, -a.y * b.x));
}
__device__ __forceinline__ float2 cadd(float2 a, float2 b) {
  return make_float2(a.x + b.x, a.y + b.y);
}
__device__ __forceinline__ float2 csub(float2 a, float2 b) {
  return make_float2(a.x - b.x, a.y - b.y);
}
__device__ __forceinline__ void swap2(float2& a, float2& b) {
  float2 t = a; a = b; b = t;
}

struct C2 { float2 e[4]; };

__device__ C2 cmm(const C2& A, const C2& B) {
  C2 R;
  #pragma unroll
  for (int r = 0; r < 2; ++r)
    #pragma unroll
    for (int c = 0; c < 2; ++c)
      R.e[r*2+c] = cadd(cmul(A.e[r*2+0], B.e[0*2+c]), cmul(A.e[r*2+1], B.e[1*2+c]));
  return R;
}
__device__ C2 gRX(float t) {
  float s = __sinf(0.5f*t), c = __cosf(0.5f*t);
  C2 M;
  M.e[0] = make_float2(c, 0.f);  M.e[1] = make_float2(0.f, -s);
  M.e[2] = make_float2(0.f, -s); M.e[3] = make_float2(c, 0.f);
  return M;
}
__device__ C2 gRY(float t) {
  float s = __sinf(0.5f*t), c = __cosf(0.5f*t);
  C2 M;
  M.e[0] = make_float2(c, 0.f);  M.e[1] = make_float2(-s, 0.f);
  M.e[2] = make_float2(s, 0.f);  M.e[3] = make_float2(c, 0.f);
  return M;
}
__device__ C2 gRZ(float t) {
  float s = __sinf(0.5f*t), c = __cosf(0.5f*t);
  C2 M;
  M.e[0] = make_float2(c, -s);    M.e[1] = make_float2(0.f, 0.f);
  M.e[2] = make_float2(0.f, 0.f); M.e[3] = make_float2(c, s);
  return M;
}
__device__ C2 gROT(float phi, float th, float om) {
  return cmm(cmm(gRZ(om), gRY(th)), gRZ(phi));
}

// One block: build ME / U0c / U1t / GP into ws.
__global__ __launch_bounds__(256) void setup_kernel(
    const float* __restrict__ strongp, const float* __restrict__ initsp,
    const float* __restrict__ updatep, float* __restrict__ ws) {
  __shared__ float2 U2s[16][17];
  const int tid = threadIdx.x;
  if (tid < 48) {
    // build U_k (k = tid>>4), column col = tid&15. bit masks: wire3=8, nb=4, w7=2, w8=1.
    const int k = tid >> 4, col = tid & 15;
    float2 u[16];
    #pragma unroll
    for (int r = 0; r < 16; ++r) u[r] = make_float2(r == col ? 1.f : 0.f, 0.f);
    #pragma unroll
    for (int l = 0; l < 2; ++l) {
      #pragma unroll
      for (int j = 0; j < 4; ++j) {
        const float* p = updatep + k*24 + l*12 + j*3;
        C2 U = gROT(p[0], p[1], p[2]);
        const int m = 8 >> j;
        #pragma unroll
        for (int r = 0; r < 16; ++r)
          if (!(r & m)) {
            float2 a0 = u[r], a1 = u[r | m];
            u[r]     = cadd(cmul(U.e[0], a0), cmul(U.e[1], a1));
            u[r | m] = cadd(cmul(U.e[2], a0), cmul(U.e[3], a1));
          }
      }
      #pragma unroll
      for (int j = 0; j < 4; ++j) {
        const int mc = 8 >> j;
        const int mt0[4] = {4, 2, 1, 8};
        const int mt1[4] = {2, 1, 8, 4};
        const int mt = (l == 0) ? mt0[j] : mt1[j];
        #pragma unroll
        for (int r = 0; r < 16; ++r)
          if ((r & mc) && !(r & mt)) swap2(u[r], u[r | mt]);
      }
    }
    if (k == 0) {
      if (!(col & 3)) {
        const int jc = col >> 2;
        #pragma unroll
        for (int r = 0; r < 16; ++r) {
          ws[U0C_F + (jc*16 + r)*2 + 0] = u[r].x;
          ws[U0C_F + (jc*16 + r)*2 + 1] = u[r].y;
        }
      }
    } else if (k == 1) {
      #pragma unroll
      for (int r = 0; r < 16; ++r) {
        ws[U1T_F + (col*16 + r)*2 + 0] = u[r].x;
        ws[U1T_F + (col*16 + r)*2 + 1] = u[r].y;
      }
    } else {
      #pragma unroll
      for (int r = 0; r < 16; ++r) U2s[col][r] = u[r];   // U2s[q][t] = U2[t][q]
    }
  }
  if (tid == 48) {
    // M_edge 4x4 (basis (b_e<<1)|b_nb)
    float2 M[4][4];
    #pragma unroll
    for (int r = 0; r < 4; ++r)
      #pragma unroll
      for (int c = 0; c < 4; ++c)
        M[r][c] = make_float2(r == c ? 1.f : 0.f, 0.f);
    auto rowpair = [&](int r0, int r1, C2 U) {
      #pragma unroll
      for (int c = 0; c < 4; ++c) {
        float2 a0 = M[r0][c], a1 = M[r1][c];
        M[r0][c] = cadd(cmul(U.e[0], a0), cmul(U.e[1], a1));
        M[r1][c] = cadd(cmul(U.e[2], a0), cmul(U.e[3], a1));
      }
    };
    auto rowswap = [&](int r0, int r1) {
      #pragma unroll
      for (int c = 0; c < 4; ++c) swap2(M[r0][c], M[r1][c]);
    };
    rowpair(1, 3, gRX(initsp[0]));
    rowpair(2, 3, gRY(initsp[1]));
    #pragma unroll
    for (int l = 0; l < 2; ++l) {
      C2 Re = gROT(strongp[l*6+0], strongp[l*6+1], strongp[l*6+2]);
      C2 Rn = gROT(strongp[l*6+3], strongp[l*6+4], strongp[l*6+5]);
      rowpair(0, 2, Re); rowpair(1, 3, Re);
      rowpair(0, 1, Rn); rowpair(2, 3, Rn);
      rowswap(2, 3);
      rowswap(1, 3);
    }
    #pragma unroll
    for (int r = 0; r < 4; ++r)
      #pragma unroll
      for (int c = 0; c < 4; ++c) {
        ws[ME_F + (r*4 + c)*2 + 0] = M[r][c].x;
        ws[ME_F + (r*4 + c)*2 + 1] = M[r][c].y;
      }
  }
  __syncthreads();
  if (tid < 64) {
    // GP[w][(c*2+n)*16 + (cp*2+np)], q = ((c&4)<<1)|(n<<2)|(c&3)
    const int c = tid >> 3, cp = tid & 7;
    #pragma unroll
    for (int n = 0; n < 2; ++n)
      #pragma unroll
      for (int np = 0; np < 2; ++np) {
        const int q  = ((c  & 4) << 1) | (n  << 2) | (c  & 3);
        const int qp = ((cp & 4) << 1) | (np << 2) | (cp & 3);
        float2 g3 = make_float2(0,0), g7 = g3, g8 = g3;
        #pragma unroll
        for (int t = 0; t < 16; ++t) {
          float2 pr = cmulc(U2s[q][t], U2s[qp][t]);
          g3 = (t & 8) ? csub(g3, pr) : cadd(g3, pr);
          g7 = (t & 2) ? csub(g7, pr) : cadd(g7, pr);
          g8 = (t & 1) ? csub(g8, pr) : cadd(g8, pr);
        }
        const int idx = (c*2 + n)*16 + (cp*2 + np);
        ws[GP_F + (0*256 + idx)*2 + 0] = g3.x;
        ws[GP_F + (0*256 + idx)*2 + 1] = g3.y;
        ws[GP_F + (1*256 + idx)*2 + 0] = g7.x;
        ws[GP_F + (1*256 + idx)*2 + 1] = g7.y;
        ws[GP_F + (2*256 + idx)*2 + 0] = g8.x;
        ws[GP_F + (2*256 + idx)*2 + 1] = g8.y;
      }
  }
}

// Everything per-UE in one wave. 4 waves/block, no __syncthreads.
__global__ __launch_bounds__(256) void mega_kernel(
    const float* __restrict__ x_ue, const float* __restrict__ x_ap,
    const float* __restrict__ edge_attr, const int* __restrict__ esrc,
    const float* __restrict__ Wn1u, const float* __restrict__ bn1u,
    const float* __restrict__ Wn2u, const float* __restrict__ bn2u,
    const float* __restrict__ Wn1a, const float* __restrict__ bn1a,
    const float* __restrict__ Wn2a, const float* __restrict__ bn2a,
    const float* __restrict__ We1,  const float* __restrict__ be1,
    const float* __restrict__ We2,  const float* __restrict__ be2,
    const float* __restrict__ ws,
    const float* __restrict__ Wu1, const float* __restrict__ bu1,
    const float* __restrict__ Wu2, const float* __restrict__ bu2,
    const float* __restrict__ lng, const float* __restrict__ lnb,
    const float* __restrict__ Wf1, const float* __restrict__ bf1,
    const float* __restrict__ Wf2, const float* __restrict__ bf2,
    const float* __restrict__ Wf3, const float* __restrict__ bf3,
    float* __restrict__ out) {
  __shared__ float2 encv[4][8];
  __shared__ float2 pr_s[4][3][4];
  __shared__ float2 psi0[4][2][16];
  __shared__ float2 psi2[4][8][16];
  __shared__ float  act[4][128];
  const int tid = threadIdx.x, wv = tid >> 6, lane = tid & 63;
  const int u = blockIdx.x*4 + wv;
  const int g = lane >> 3, sub = lane & 7;

  // ---- inline encoders: 8-lane group per row (g: 0=ue, 1-3=ea_i, 4-6=ap_i, 7=dup) ----
  const float* xptr; const float* W1; const float* b1p; const float* W2; const float* b2p; int D;
  if (g >= 4 && g < 7) {
    const int s = esrc[u*3 + (g - 4)];
    xptr = x_ap + s*8;                 W1 = Wn1a; b1p = bn1a; W2 = Wn2a; b2p = bn2a; D = 8;
  } else if (g >= 1 && g < 4) {
    xptr = edge_attr + (u*3 + (g-1))*4; W1 = We1;  b1p = be1;  W2 = We2;  b2p = be2;  D = 4;
  } else {
    xptr = x_ue + u*8;                 W1 = Wn1u; b1p = bn1u; W2 = Wn2u; b2p = bn2u; D = 8;
  }
  float xk[8];
  #pragma unroll
  for (int k = 0; k < 8; ++k) {
    const float v = xptr[k < D ? k : D-1];
    xk[k] = (k < D) ? v : 0.f;
  }
  {
    float o0 = 0.f, o1 = 0.f;
    #pragma unroll
    for (int jj = 0; jj < 8; ++jj) {
      const int j = jj*16 + sub*2;
      float2 h = *(const float2*)(b1p + j);
      #pragma unroll
      for (int k = 0; k < 8; ++k) {
        const float2 w = *(const float2*)(W1 + (k < D ? k : D-1)*128 + j);
        h.x = fmaf(xk[k], w.x, h.x);
        h.y = fmaf(xk[k], w.y, h.y);
      }
      h.x = LEAKY(h.x); h.y = LEAKY(h.y);
      const float2 wa = *(const float2*)(W2 + j*2);
      const float2 wb = *(const float2*)(W2 + j*2 + 2);
      o0 = fmaf(h.x, wa.x, fmaf(h.y, wb.x, o0));
      o1 = fmaf(h.x, wa.y, fmaf(h.y, wb.y, o1));
    }
    o0 += __shfl_xor(o0, 1); o1 += __shfl_xor(o1, 1);
    o0 += __shfl_xor(o0, 2); o1 += __shfl_xor(o1, 2);
    o0 += __shfl_xor(o0, 4); o1 += __shfl_xor(o1, 4);
    if (sub == 0 && g < 7) encv[wv][g] = make_float2(o0 + b2p[0], o1 + b2p[1]);
  }

  auto mkv = [](float aa, float bb, float2& v0, float2& v1) {
    const float sa = __sinf(0.5f*aa), ca = __cosf(0.5f*aa);
    const float sb = __sinf(0.5f*bb), cb = __cosf(0.5f*bb);
    v0 = make_float2(cb*ca, -sb*ca);
    v1 = make_float2(sa*sb, -sa*cb);
  };
  const float2 ue_ab = encv[wv][0];
  float2 t0, t1;
  mkv(ue_ab.x, ue_ab.y, t0, t1);

  const float2* MEp  = (const float2*)ws;          // 16
  const float2* U0cp = (const float2*)ws + 16;     // 64  [j][r]
  const float2* U1tp = (const float2*)ws + 80;     // 256 [q][r]
  const float2* GPp  = (const float2*)ws + 336;    // 768

  // ---- pairs (12 lanes) ----
  if (lane < 12) {
    const int i = lane >> 2, r = lane & 3;
    const float2 eab = encv[wv][1 + i];
    const float2 nab = encv[wv][4 + i];
    float2 e0, e1, n0, n1;
    mkv(eab.x, eab.y, e0, e1);
    mkv(nab.x, nab.y, n0, n1);
    float2 in4[4] = {cmul(e0,n0), cmul(e0,n1), cmul(e1,n0), cmul(e1,n1)};
    float2 acc = make_float2(0.f, 0.f);
    #pragma unroll
    for (int cc = 0; cc < 4; ++cc) acc = cadd(acc, cmul(MEp[r*4 + cc], in4[cc]));
    pr_s[wv][i][r] = acc;
  }

  // ---- block0: psi0 (lanes 0..31) ----
  if (lane < 32) {
    const int b = lane >> 4, row = lane & 15;
    float2 acc = make_float2(0.f, 0.f);
    #pragma unroll
    for (int j = 0; j < 4; ++j) {
      const float2 phi = pr_s[wv][0][(b << 1) | (j & 1)];
      const float2 coef = cmul((j >> 1) ? t1 : t0, phi);
      acc = cadd(acc, cmul(U0cp[j*16 + row], coef));
    }
    psi0[wv][b][row] = acc;
  }

  // ---- block1: psi2 (all lanes, 2 rows each) ----
  {
    const int ibr = lane >> 3, rp = lane & 7;
    const int db = ibr >> 2, da = (ibr >> 1) & 1, dbp = ibr & 1;
    const float2 f10 = pr_s[wv][1][(dbp << 1) | 0];
    const float2 f11 = pr_s[wv][1][(dbp << 1) | 1];
    float2 chi[8];
    {
      const float4 a0 = *(const float4*)&psi0[wv][db][da*4 + 0];
      const float4 a1 = *(const float4*)&psi0[wv][db][da*4 + 2];
      const float4 a2 = *(const float4*)&psi0[wv][db][8 + da*4 + 0];
      const float4 a3 = *(const float4*)&psi0[wv][db][8 + da*4 + 2];
      chi[0] = make_float2(a0.x, a0.y); chi[1] = make_float2(a0.z, a0.w);
      chi[2] = make_float2(a1.x, a1.y); chi[3] = make_float2(a1.z, a1.w);
      chi[4] = make_float2(a2.x, a2.y); chi[5] = make_float2(a2.z, a2.w);
      chi[6] = make_float2(a3.x, a3.y); chi[7] = make_float2(a3.z, a3.w);
    }
    float2 q0 = make_float2(0.f, 0.f), q1 = q0;
    #pragma unroll
    for (int q = 0; q < 16; ++q) {
      const int cc = ((q >> 3) << 2) | (q & 3);
      const float2 xq = cmul(chi[cc], (q & 4) ? f11 : f10);
      q0 = cadd(q0, cmul(U1tp[q*16 + rp],     xq));
      q1 = cadd(q1, cmul(U1tp[q*16 + rp + 8], xq));
    }
    psi2[wv][ibr][rp]     = q0;
    psi2[wv][ibr][rp + 8] = q1;
  }

  // ---- R[c,cp] ----
  const int c = lane >> 3, cp = lane & 7;
  const int mc0 = ((c  & 4) << 1) | (c  & 3);
  const int mp0 = ((cp & 4) << 1) | (cp & 3);
  float2 R = make_float2(0.f, 0.f);
  #pragma unroll
  for (int br = 0; br < 8; ++br) {
    const float2 z10 = psi2[wv][br][mc0],     z11 = psi2[wv][br][mc0 + 4];
    const float2 z20 = psi2[wv][br][mp0],     z21 = psi2[wv][br][mp0 + 4];
    R.x += z10.x*z20.x + z10.y*z20.y + z11.x*z21.x + z11.y*z21.y;
    R.y += z10.y*z20.x - z10.x*z20.y + z11.y*z21.x - z11.x*z21.y;
  }

  // ---- rho2, K_w, ev ----
  const float4 f2a = *(const float4*)&pr_s[wv][2][0];
  const float4 f2b = *(const float4*)&pr_s[wv][2][2];
  const float2 f20 = make_float2(f2a.x, f2a.y), f21 = make_float2(f2a.z, f2a.w);
  const float2 f22 = make_float2(f2b.x, f2b.y), f23 = make_float2(f2b.z, f2b.w);
  const float2 rho00 = make_float2(f20.x*f20.x + f20.y*f20.y + f22.x*f22.x + f22.y*f22.y, 0.f);
  const float2 rho11 = make_float2(f21.x*f21.x + f21.y*f21.y + f23.x*f23.x + f23.y*f23.y, 0.f);
  const float2 rho01 = make_float2(fmaf(f20.x,f21.x,f20.y*f21.y) + fmaf(f22.x,f23.x,f22.y*f23.y),
                                   (f20.y*f21.x - f20.x*f21.y) + (f22.y*f23.x - f22.x*f23.y));
  const float2 rho10 = make_float2(rho01.x, -rho01.y);

  float ev0, ev1, ev2;
  {
    const int base = (c*2)*16 + (cp*2);
    #pragma unroll
    for (int w = 0; w < 3; ++w) {
      const float2 g00 = GPp[w*256 + base];           // n=0,np=0 -> rho00
      const float2 g01 = GPp[w*256 + base + 1];       // n=0,np=1 -> rho10
      const float2 g10 = GPp[w*256 + base + 16];      // n=1,np=0 -> rho01
      const float2 g11 = GPp[w*256 + base + 17];      // n=1,np=1 -> rho11
      float2 K = cmul(g00, rho00);
      K = cadd(K, cmul(g01, rho10));
      K = cadd(K, cmul(g10, rho01));
      K = cadd(K, cmul(g11, rho11));
      const float e = K.x*R.x + K.y*R.y;
      if (w == 0) ev0 = e; else if (w == 1) ev1 = e; else ev2 = e;
    }
  }
  #pragma unroll
  for (int o = 32; o; o >>= 1) {
    ev0 += __shfl_xor(ev0, o);
    ev1 += __shfl_xor(ev1, o);
    ev2 += __shfl_xor(ev2, o);
  }

  // ---- Wu MLP + residual + LN ----
  const int j1 = lane, j2 = lane + 64;
  const float in5[5] = {ue_ab.x, ue_ab.y, ev0, ev1, ev2};
  float h1 = bu1[j1], h2 = bu1[j2];
  #pragma unroll
  for (int k = 0; k < 5; ++k) {
    h1 = fmaf(in5[k], Wu1[k*128 + j1], h1);
    h2 = fmaf(in5[k], Wu1[k*128 + j2], h2);
  }
  h1 = LEAKY(h1); h2 = LEAKY(h2);
  const float2 wu2a = *(const float2*)(Wu2 + j1*2);
  const float2 wu2b = *(const float2*)(Wu2 + j2*2);
  float p0 = fmaf(h1, wu2a.x, h2*wu2b.x);
  float p1 = fmaf(h1, wu2a.y, h2*wu2b.y);
  #pragma unroll
  for (int o = 32; o; o >>= 1) { p0 += __shfl_xor(p0, o); p1 += __shfl_xor(p1, o); }
  const float hh0 = ue_ab.x + p0 + bu2[0];
  const float hh1 = ue_ab.y + p1 + bu2[1];
  const float mu = 0.5f*(hh0 + hh1);
  const float dd = hh0 - mu;
  const float inv = rsqrtf(dd*dd + 1e-5f);
  const float g0 =  dd*inv*lng[0] + lnb[0];
  const float g1 = -dd*inv*lng[1] + lnb[1];

  // ---- head: 2 -> 128 -> 128 -> 2 + sigmoid ----
  const float a1f = LEAKY(fmaf(g0, Wf1[j1], fmaf(g1, Wf1[128 + j1], bf1[j1])));
  const float a2f = LEAKY(fmaf(g0, Wf1[j2], fmaf(g1, Wf1[128 + j2], bf1[j2])));
  act[wv][j1] = a1f;
  act[wv][j2] = a2f;
  const float2 bb2 = *(const float2*)(bf2 + 2*lane);
  float h2a = bb2.x, h2b = bb2.y;
  #pragma unroll 8
  for (int kk = 0; kk < 32; ++kk) {
    const float4 a4 = *(const float4*)&act[wv][kk*4];
    const float av[4] = {a4.x, a4.y, a4.z, a4.w};
    #pragma unroll
    for (int t = 0; t < 4; ++t) {
      const float2 w = *(const float2*)(Wf2 + (kk*4 + t)*128 + 2*lane);
      h2a = fmaf(av[t], w.x, h2a);
      h2b = fmaf(av[t], w.y, h2b);
    }
  }
  const float hva = LEAKY(h2a), hvb = LEAKY(h2b);
  const float4 w3 = *(const float4*)(Wf3 + 4*lane);
  float o0 = fmaf(hva, w3.x, hvb*w3.z);
  float o1 = fmaf(hva, w3.y, hvb*w3.w);
  #pragma unroll
  for (int o = 32; o; o >>= 1) { o0 += __shfl_xor(o0, o); o1 += __shfl_xor(o1, o); }
  if (lane == 0) {
    const float s0 = 1.f/(1.f + __expf(-(o0 + bf3[0])));
    const float s1 = 1.f/(1.f + __expf(-(o1 + bf3[1])));
    *(float2*)(out + u*2) = make_float2(s0, s1);
  }
}

extern "C" void kernel_launch(void* const* d_in, const int* in_sizes, int n_in,
                              void* d_out, int out_size, void* d_ws, size_t ws_size,
                              hipStream_t stream) {
  (void)in_sizes; (void)n_in; (void)out_size; (void)ws_size;
  const float* x_ue      = (const float*)d_in[0];
  const float* x_ap      = (const float*)d_in[1];
  const float* edge_attr = (const float*)d_in[2];
  const int*   edge_src  = (const int*)d_in[3];
  const float* Wn1u = (const float*)d_in[5];
  const float* bn1u = (const float*)d_in[6];
  const float* Wn2u = (const float*)d_in[7];
  const float* bn2u = (const float*)d_in[8];
  const float* Wn1a = (const float*)d_in[9];
  const float* bn1a = (const float*)d_in[10];
  const float* Wn2a = (const float*)d_in[11];
  const float* bn2a = (const float*)d_in[12];
  const float* We1  = (const float*)d_in[13];
  const float* be1  = (const float*)d_in[14];
  const float* We2  = (const float*)d_in[15];
  const float* be2  = (const float*)d_in[16];
  const float* strong = (const float*)d_in[17];
  const float* inits  = (const float*)d_in[18];
  const float* update = (const float*)d_in[19];
  const float* Wu1  = (const float*)d_in[20];
  const float* bu1  = (const float*)d_in[21];
  const float* Wu2  = (const float*)d_in[22];
  const float* bu2  = (const float*)d_in[23];
  const float* ln_g = (const float*)d_in[24];
  const float* ln_b = (const float*)d_in[25];
  const float* Wf1  = (const float*)d_in[26];
  const float* bf1  = (const float*)d_in[27];
  const float* Wf2  = (const float*)d_in[28];
  const float* bf2  = (const float*)d_in[29];
  const float* Wf3  = (const float*)d_in[30];
  const float* bf3  = (const float*)d_in[31];

  float* ws = (float*)d_ws;

  setup_kernel<<<1, 256, 0, stream>>>(strong, inits, update, ws);
  mega_kernel<<<2048, 256, 0, stream>>>(x_ue, x_ap, edge_attr, edge_src,
                                        Wn1u, bn1u, Wn2u, bn2u,
                                        Wn1a, bn1a, Wn2a, bn2a,
                                        We1, be1, We2, be2,
                                        ws,
                                        Wu1, bu1, Wu2, bu2, ln_g, ln_b,
                                        Wf1, bf1, Wf2, bf2, Wf3, bf3,
                                        (float*)d_out);
}

// Round 7
// 48.302 us; speedup vs baseline: 1.5581x; 1.5581x over previous
//
#include <hip/hip_runtime.h>

#define LEAKY(x) ((x) > 0.0f ? (x) : 0.01f * (x))

// ws float layout
#define CONST_F 0      // ME[32] U0c[128] U1t[512] GP[1536] = 2208 floats
#define GP_F    672    // float offset of GP within ws
#define AP_F    2208   // ap_enc: 4096 floats
#define G_F     6304   // g: 16384 floats

__device__ __forceinline__ float2 cmul(float2 a, float2 b) {
  return make_float2(fmaf(a.x, b.x, -a.y * b.y), fmaf(a.x, b.y, a.y * b.x));
}
__device__ __forceinline__ float2 cmulc(float2 a, float2 b) {  // conj(a)*b
  return make_float2(fmaf(a.x, b.x, a.y * b.y), fmaf(a.x, b.y, -a.y * b.x));
}
__device__ __forceinline__ float2 cadd(float2 a, float2 b) {
  return make_float2(a.x + b.x, a.y + b.y);
}
__device__ __forceinline__ float2 csub(float2 a, float2 b) {
  return make_float2(a.x - b.x, a.y - b.y);
}
__device__ __forceinline__ void swap2(float2& a, float2& b) {
  float2 t = a; a = b; b = t;
}

struct C2 { float2 e[4]; };

__device__ C2 cmm(const C2& A, const C2& B) {
  C2 R;
  #pragma unroll
  for (int r = 0; r < 2; ++r)
    #pragma unroll
    for (int c = 0; c < 2; ++c)
      R.e[r*2+c] = cadd(cmul(A.e[r*2+0], B.e[0*2+c]), cmul(A.e[r*2+1], B.e[1*2+c]));
  return R;
}
__device__ C2 gRX(float t) {
  float s = __sinf(0.5f*t), c = __cosf(0.5f*t);
  C2 M;
  M.e[0] = make_float2(c, 0.f);  M.e[1] = make_float2(0.f, -s);
  M.e[2] = make_float2(0.f, -s); M.e[3] = make_float2(c, 0.f);
  return M;
}
__device__ C2 gRY(float t) {
  float s = __sinf(0.5f*t), c = __cosf(0.5f*t);
  C2 M;
  M.e[0] = make_float2(c, 0.f);  M.e[1] = make_float2(-s, 0.f);
  M.e[2] = make_float2(s, 0.f);  M.e[3] = make_float2(c, 0.f);
  return M;
}
__device__ C2 gRZ(float t) {
  float s = __sinf(0.5f*t), c = __cosf(0.5f*t);
  C2 M;
  M.e[0] = make_float2(c, -s);    M.e[1] = make_float2(0.f, 0.f);
  M.e[2] = make_float2(0.f, 0.f); M.e[3] = make_float2(c, s);
  return M;
}
__device__ C2 gROT(float phi, float th, float om) {
  return cmm(cmm(gRZ(om), gRY(th)), gRZ(phi));
}

// blocks 0..63: AP encode (32 rows/block, 8 threads/row). block 64: gate algebra.
__global__ __launch_bounds__(256) void setup_kernel(
    const float* __restrict__ x_ap,
    const float* __restrict__ Wn1a, const float* __restrict__ bn1a,
    const float* __restrict__ Wn2a, const float* __restrict__ bn2a,
    const float* __restrict__ strongp, const float* __restrict__ initsp,
    const float* __restrict__ updatep, float* __restrict__ ws) {
  const int bi = blockIdx.x, tid = threadIdx.x;
  if (bi < 64) {
    const int r = bi*32 + (tid >> 3), sub = tid & 7;
    float xi[8];
    #pragma unroll
    for (int k = 0; k < 8; ++k) xi[k] = x_ap[r*8 + k];
    float o0 = 0.f, o1 = 0.f;
    #pragma unroll
    for (int jj = 0; jj < 16; ++jj) {
      const int j = jj*8 + sub;
      float h = bn1a[j];
      #pragma unroll
      for (int k = 0; k < 8; ++k) h = fmaf(xi[k], Wn1a[k*128 + j], h);
      h = LEAKY(h);
      o0 = fmaf(h, Wn2a[j*2 + 0], o0);
      o1 = fmaf(h, Wn2a[j*2 + 1], o1);
    }
    #pragma unroll
    for (int o = 4; o; o >>= 1) { o0 += __shfl_xor(o0, o); o1 += __shfl_xor(o1, o); }
    if (sub == 0)
      *(float2*)(ws + AP_F + r*2) = make_float2(o0 + bn2a[0], o1 + bn2a[1]);
    return;
  }
  // ---- gate algebra ----
  __shared__ float2 U2s[16][17];
  if (tid < 48) {
    // U_k (k=tid>>4), column col=tid&15. bit masks: wire3=8, nb=4, w7=2, w8=1.
    const int k = tid >> 4, col = tid & 15;
    float2 u[16];
    #pragma unroll
    for (int r = 0; r < 16; ++r) u[r] = make_float2(r == col ? 1.f : 0.f, 0.f);
    #pragma unroll
    for (int l = 0; l < 2; ++l) {
      #pragma unroll
      for (int j = 0; j < 4; ++j) {
        const float* p = updatep + k*24 + l*12 + j*3;
        C2 U = gROT(p[0], p[1], p[2]);
        const int m = 8 >> j;
        #pragma unroll
        for (int r = 0; r < 16; ++r)
          if (!(r & m)) {
            float2 a0 = u[r], a1 = u[r | m];
            u[r]     = cadd(cmul(U.e[0], a0), cmul(U.e[1], a1));
            u[r | m] = cadd(cmul(U.e[2], a0), cmul(U.e[3], a1));
          }
      }
      #pragma unroll
      for (int j = 0; j < 4; ++j) {
        const int mc = 8 >> j;
        const int mt0[4] = {4, 2, 1, 8};
        const int mt1[4] = {2, 1, 8, 4};
        const int mt = (l == 0) ? mt0[j] : mt1[j];
        #pragma unroll
        for (int r = 0; r < 16; ++r)
          if ((r & mc) && !(r & mt)) swap2(u[r], u[r | mt]);
      }
    }
    if (k == 0) {
      if (!(col & 3)) {
        const int jc = col >> 2;
        #pragma unroll
        for (int r = 0; r < 16; ++r) {
          ws[32 + (jc*16 + r)*2 + 0] = u[r].x;
          ws[32 + (jc*16 + r)*2 + 1] = u[r].y;
        }
      }
    } else if (k == 1) {
      #pragma unroll
      for (int r = 0; r < 16; ++r) {
        ws[160 + (col*16 + r)*2 + 0] = u[r].x;
        ws[160 + (col*16 + r)*2 + 1] = u[r].y;
      }
    } else {
      #pragma unroll
      for (int r = 0; r < 16; ++r) U2s[col][r] = u[r];   // U2s[q][t] = U2[t][q]
    }
  }
  if (tid == 48) {
    // M_edge 4x4 (basis (b_e<<1)|b_nb)
    float2 M[4][4];
    #pragma unroll
    for (int r = 0; r < 4; ++r)
      #pragma unroll
      for (int c = 0; c < 4; ++c)
        M[r][c] = make_float2(r == c ? 1.f : 0.f, 0.f);
    auto rowpair = [&](int r0, int r1, C2 U) {
      #pragma unroll
      for (int c = 0; c < 4; ++c) {
        float2 a0 = M[r0][c], a1 = M[r1][c];
        M[r0][c] = cadd(cmul(U.e[0], a0), cmul(U.e[1], a1));
        M[r1][c] = cadd(cmul(U.e[2], a0), cmul(U.e[3], a1));
      }
    };
    auto rowswap = [&](int r0, int r1) {
      #pragma unroll
      for (int c = 0; c < 4; ++c) swap2(M[r0][c], M[r1][c]);
    };
    rowpair(1, 3, gRX(initsp[0]));
    rowpair(2, 3, gRY(initsp[1]));
    #pragma unroll
    for (int l = 0; l < 2; ++l) {
      C2 Re = gROT(strongp[l*6+0], strongp[l*6+1], strongp[l*6+2]);
      C2 Rn = gROT(strongp[l*6+3], strongp[l*6+4], strongp[l*6+5]);
      rowpair(0, 2, Re); rowpair(1, 3, Re);
      rowpair(0, 1, Rn); rowpair(2, 3, Rn);
      rowswap(2, 3);
      rowswap(1, 3);
    }
    #pragma unroll
    for (int r = 0; r < 4; ++r)
      #pragma unroll
      for (int c = 0; c < 4; ++c) {
        ws[(r*4 + c)*2 + 0] = M[r][c].x;
        ws[(r*4 + c)*2 + 1] = M[r][c].y;
      }
  }
  __syncthreads();
  {
    // GP: 256 threads, one (c,cp,n,np) each, 3 wires.
    const int c = tid >> 5, cp = (tid >> 2) & 7, n = (tid >> 1) & 1, np = tid & 1;
    const int q  = ((c  & 4) << 1) | (n  << 2) | (c  & 3);
    const int qp = ((cp & 4) << 1) | (np << 2) | (cp & 3);
    float2 g3 = make_float2(0,0), g7 = g3, g8 = g3;
    #pragma unroll
    for (int t = 0; t < 16; ++t) {
      float2 pr = cmulc(U2s[q][t], U2s[qp][t]);
      g3 = (t & 8) ? csub(g3, pr) : cadd(g3, pr);
      g7 = (t & 2) ? csub(g7, pr) : cadd(g7, pr);
      g8 = (t & 1) ? csub(g8, pr) : cadd(g8, pr);
    }
    const int idx = (c*2 + n)*16 + (cp*2 + np);
    ws[GP_F + (0*256 + idx)*2 + 0] = g3.x;
    ws[GP_F + (0*256 + idx)*2 + 1] = g3.y;
    ws[GP_F + (1*256 + idx)*2 + 0] = g7.x;
    ws[GP_F + (1*256 + idx)*2 + 1] = g7.y;
    ws[GP_F + (2*256 + idx)*2 + 0] = g8.x;
    ws[GP_F + (2*256 + idx)*2 + 1] = g8.y;
  }
}

// 4 UEs/block (1/wave). Consts + UE/edge encoder weights staged in LDS.
__global__ __launch_bounds__(256) void mega_kernel(
    const float* __restrict__ x_ue, const float* __restrict__ edge_attr,
    const int* __restrict__ esrc,
    const float* __restrict__ Wn1u, const float* __restrict__ bn1u,
    const float* __restrict__ Wn2u, const float* __restrict__ bn2u,
    const float* __restrict__ We1,  const float* __restrict__ be1,
    const float* __restrict__ We2,  const float* __restrict__ be2,
    float* __restrict__ ws,
    const float* __restrict__ Wu1, const float* __restrict__ bu1,
    const float* __restrict__ Wu2, const float* __restrict__ bu2,
    const float* __restrict__ lng, const float* __restrict__ lnb) {
  __shared__ __align__(16) float2 cst[1104];   // ME 16 | U0c 64 | U1t 256 | GP 768
  __shared__ __align__(16) float w1u[1024];
  __shared__ __align__(16) float w1e[512];
  __shared__ __align__(16) float b1u[128], b1e[128];
  __shared__ __align__(16) float2 w2u[128], w2e[128];
  __shared__ __align__(16) float2 encv[4][4];
  __shared__ __align__(16) float2 pr_s[4][3][4];
  __shared__ __align__(16) float2 psi0[4][2][16];
  __shared__ __align__(16) float2 psi2[4][8][16];
  const int tid = threadIdx.x, wv = tid >> 6, lane = tid & 63;
  const int u = blockIdx.x*4 + wv;

  // ---- stage (FIXED: w2u/w2e are 64 float4 each) ----
  {
    const float4* s4 = (const float4*)ws;
    float4* d4 = (float4*)cst;
    #pragma unroll
    for (int i = tid; i < 552; i += 256) d4[i] = s4[i];
    ((float4*)w1u)[tid] = ((const float4*)Wn1u)[tid];
    if (tid < 128)      ((float4*)w1e)[tid]     = ((const float4*)We1)[tid];
    else if (tid < 160) ((float4*)b1u)[tid-128] = ((const float4*)bn1u)[tid-128];
    else if (tid < 192) ((float4*)b1e)[tid-160] = ((const float4*)be1)[tid-160];
    else                ((float4*)w2u)[tid-192] = ((const float4*)Wn2u)[tid-192]; // 64
    if (tid < 64)       ((float4*)w2e)[tid]     = ((const float4*)We2)[tid];      // 64
  }
  __syncthreads();

  const float2* MEl  = cst;
  const float2* U0cl = cst + 16;
  const float2* U1tl = cst + 80;
  const float2* GPl  = cst + 336;

  // ---- encoders: 16 lanes per row; eg 0 = ue, 1..3 = ea_i ----
  const int eg = lane >> 4, s16 = lane & 15;
  {
    float o0 = 0.f, o1 = 0.f;
    if (eg == 0) {
      const float4 xa = *(const float4*)(x_ue + u*8);
      const float4 xb = *(const float4*)(x_ue + u*8 + 4);
      #pragma unroll
      for (int jj = 0; jj < 8; ++jj) {
        const int j = jj*16 + s16;
        float h = b1u[j];
        h = fmaf(xa.x, w1u[0*128+j], h); h = fmaf(xa.y, w1u[1*128+j], h);
        h = fmaf(xa.z, w1u[2*128+j], h); h = fmaf(xa.w, w1u[3*128+j], h);
        h = fmaf(xb.x, w1u[4*128+j], h); h = fmaf(xb.y, w1u[5*128+j], h);
        h = fmaf(xb.z, w1u[6*128+j], h); h = fmaf(xb.w, w1u[7*128+j], h);
        h = LEAKY(h);
        const float2 w2 = w2u[j];
        o0 = fmaf(h, w2.x, o0); o1 = fmaf(h, w2.y, o1);
      }
    } else {
      const float4 xa = *(const float4*)(edge_attr + (u*3 + eg - 1)*4);
      #pragma unroll
      for (int jj = 0; jj < 8; ++jj) {
        const int j = jj*16 + s16;
        float h = b1e[j];
        h = fmaf(xa.x, w1e[0*128+j], h); h = fmaf(xa.y, w1e[1*128+j], h);
        h = fmaf(xa.z, w1e[2*128+j], h); h = fmaf(xa.w, w1e[3*128+j], h);
        h = LEAKY(h);
        const float2 w2 = w2e[j];
        o0 = fmaf(h, w2.x, o0); o1 = fmaf(h, w2.y, o1);
      }
    }
    o0 += __shfl_xor(o0, 1); o1 += __shfl_xor(o1, 1);
    o0 += __shfl_xor(o0, 2); o1 += __shfl_xor(o1, 2);
    o0 += __shfl_xor(o0, 4); o1 += __shfl_xor(o1, 4);
    o0 += __shfl_xor(o0, 8); o1 += __shfl_xor(o1, 8);
    if (s16 == 0) {
      const float b20 = (eg == 0) ? bn2u[0] : be2[0];
      const float b21 = (eg == 0) ? bn2u[1] : be2[1];
      encv[wv][eg] = make_float2(o0 + b20, o1 + b21);
    }
  }

  auto mkv = [](float aa, float bb, float2& v0, float2& v1) {
    const float sa = __sinf(0.5f*aa), ca = __cosf(0.5f*aa);
    const float sb = __sinf(0.5f*bb), cb = __cosf(0.5f*bb);
    v0 = make_float2(cb*ca, -sb*ca);
    v1 = make_float2(sa*sb, -sa*cb);
  };
  const float2 ue_ab = encv[wv][0];
  float2 t0, t1;
  mkv(ue_ab.x, ue_ab.y, t0, t1);

  // ---- pairs (lanes 0..11): i = lane>>2, r = lane&3 ----
  if (lane < 12) {
    const int i = lane >> 2, r = lane & 3;
    const float2 eab = encv[wv][1 + i];
    const int s = esrc[u*3 + i];
    const float2 nab = *(const float2*)(ws + AP_F + s*2);
    float2 e0, e1, n0, n1;
    mkv(eab.x, eab.y, e0, e1);
    mkv(nab.x, nab.y, n0, n1);
    float2 in4[4] = {cmul(e0,n0), cmul(e0,n1), cmul(e1,n0), cmul(e1,n1)};
    float2 acc = make_float2(0.f, 0.f);
    #pragma unroll
    for (int cc = 0; cc < 4; ++cc) acc = cadd(acc, cmul(MEl[r*4 + cc], in4[cc]));
    pr_s[wv][i][r] = acc;
  }

  // ---- block0: psi0 (lanes 0..31) ----
  if (lane < 32) {
    const int b = lane >> 4, row = lane & 15;
    float2 acc = make_float2(0.f, 0.f);
    #pragma unroll
    for (int j = 0; j < 4; ++j) {
      const float2 phi = pr_s[wv][0][(b << 1) | (j & 1)];
      const float2 coef = cmul((j >> 1) ? t1 : t0, phi);
      acc = cadd(acc, cmul(U0cl[j*16 + row], coef));
    }
    psi0[wv][b][row] = acc;
  }

  // ---- block1: psi2 (all lanes, 2 rows each) ----
  {
    const int ibr = lane >> 3, rp = lane & 7;
    const int db = ibr >> 2, da = (ibr >> 1) & 1, dbp = ibr & 1;
    const float2 f10 = pr_s[wv][1][(dbp << 1) | 0];
    const float2 f11 = pr_s[wv][1][(dbp << 1) | 1];
    float2 chi[8];
    {
      const float4 a0 = *(const float4*)&psi0[wv][db][da*4 + 0];
      const float4 a1 = *(const float4*)&psi0[wv][db][da*4 + 2];
      const float4 a2 = *(const float4*)&psi0[wv][db][8 + da*4 + 0];
      const float4 a3 = *(const float4*)&psi0[wv][db][8 + da*4 + 2];
      chi[0] = make_float2(a0.x, a0.y); chi[1] = make_float2(a0.z, a0.w);
      chi[2] = make_float2(a1.x, a1.y); chi[3] = make_float2(a1.z, a1.w);
      chi[4] = make_float2(a2.x, a2.y); chi[5] = make_float2(a2.z, a2.w);
      chi[6] = make_float2(a3.x, a3.y); chi[7] = make_float2(a3.z, a3.w);
    }
    float2 q0 = make_float2(0.f, 0.f), q1 = q0;
    #pragma unroll
    for (int q = 0; q < 16; ++q) {
      const int cc = ((q >> 3) << 2) | (q & 3);
      const float2 xq = cmul(chi[cc], (q & 4) ? f11 : f10);
      q0 = cadd(q0, cmul(U1tl[q*16 + rp],     xq));
      q1 = cadd(q1, cmul(U1tl[q*16 + rp + 8], xq));
    }
    psi2[wv][ibr][rp]     = q0;
    psi2[wv][ibr][rp + 8] = q1;
  }

  // ---- R[c,cp] ----
  const int c = lane >> 3, cp = lane & 7;
  const int mc0 = ((c  & 4) << 1) | (c  & 3);
  const int mp0 = ((cp & 4) << 1) | (cp & 3);
  float2 R = make_float2(0.f, 0.f);
  #pragma unroll
  for (int br = 0; br < 8; ++br) {
    const float2 z10 = psi2[wv][br][mc0], z11 = psi2[wv][br][mc0 + 4];
    const float2 z20 = psi2[wv][br][mp0], z21 = psi2[wv][br][mp0 + 4];
    R.x += z10.x*z20.x + z10.y*z20.y + z11.x*z21.x + z11.y*z21.y;
    R.y += z10.y*z20.x - z10.x*z20.y + z11.y*z21.x - z11.x*z21.y;
  }

  // ---- rho2, K_w, ev ----
  const float4 f2a = *(const float4*)&pr_s[wv][2][0];
  const float4 f2b = *(const float4*)&pr_s[wv][2][2];
  const float2 f20 = make_float2(f2a.x, f2a.y), f21 = make_float2(f2a.z, f2a.w);
  const float2 f22 = make_float2(f2b.x, f2b.y), f23 = make_float2(f2b.z, f2b.w);
  const float2 rho00 = make_float2(f20.x*f20.x + f20.y*f20.y + f22.x*f22.x + f22.y*f22.y, 0.f);
  const float2 rho11 = make_float2(f21.x*f21.x + f21.y*f21.y + f23.x*f23.x + f23.y*f23.y, 0.f);
  const float2 rho01 = make_float2(fmaf(f20.x,f21.x,f20.y*f21.y) + fmaf(f22.x,f23.x,f22.y*f23.y),
                                   (f20.y*f21.x - f20.x*f21.y) + (f22.y*f23.x - f22.x*f23.y));
  const float2 rho10 = make_float2(rho01.x, -rho01.y);

  float ev0, ev1, ev2;
  {
    const int base = (c*2)*16 + (cp*2);
    #pragma unroll
    for (int w = 0; w < 3; ++w) {
      const float2 g00 = GPl[w*256 + base];
      const float2 g01 = GPl[w*256 + base + 1];
      const float2 g10 = GPl[w*256 + base + 16];
      const float2 g11 = GPl[w*256 + base + 17];
      float2 K = cmul(g00, rho00);
      K = cadd(K, cmul(g01, rho10));
      K = cadd(K, cmul(g10, rho01));
      K = cadd(K, cmul(g11, rho11));
      const float e = K.x*R.x + K.y*R.y;
      if (w == 0) ev0 = e; else if (w == 1) ev1 = e; else ev2 = e;
    }
  }
  #pragma unroll
  for (int o = 32; o; o >>= 1) {
    ev0 += __shfl_xor(ev0, o);
    ev1 += __shfl_xor(ev1, o);
    ev2 += __shfl_xor(ev2, o);
  }

  // ---- Wu MLP + residual + LN -> g ----
  const int j1 = lane, j2 = lane + 64;
  const float in5[5] = {ue_ab.x, ue_ab.y, ev0, ev1, ev2};
  float h1 = bu1[j1], h2 = bu1[j2];
  #pragma unroll
  for (int k = 0; k < 5; ++k) {
    h1 = fmaf(in5[k], Wu1[k*128 + j1], h1);
    h2 = fmaf(in5[k], Wu1[k*128 + j2], h2);
  }
  h1 = LEAKY(h1); h2 = LEAKY(h2);
  const float2 wu2a = *(const float2*)(Wu2 + j1*2);
  const float2 wu2b = *(const float2*)(Wu2 + j2*2);
  float p0 = fmaf(h1, wu2a.x, h2*wu2b.x);
  float p1 = fmaf(h1, wu2a.y, h2*wu2b.y);
  #pragma unroll
  for (int o = 32; o; o >>= 1) { p0 += __shfl_xor(p0, o); p1 += __shfl_xor(p1, o); }
  if (lane == 0) {
    const float hh0 = ue_ab.x + p0 + bu2[0];
    const float hh1 = ue_ab.y + p1 + bu2[1];
    const float mu = 0.5f*(hh0 + hh1);
    const float dd = hh0 - mu;
    const float inv = rsqrtf(dd*dd + 1e-5f);
    const float g0 =  dd*inv*lng[0] + lnb[0];
    const float g1 = -dd*inv*lng[1] + lnb[1];
    *(float2*)(ws + G_F + u*2) = make_float2(g0, g1);
  }
}

// head: 16 rows/block, 16 threads/row, 8 cols/thread.
__global__ __launch_bounds__(256) void head_kernel(
    const float* __restrict__ g,
    const float* __restrict__ Wf1, const float* __restrict__ bf1,
    const float* __restrict__ Wf2, const float* __restrict__ bf2,
    const float* __restrict__ Wf3, const float* __restrict__ bf3,
    float* __restrict__ out) {
  __shared__ float act[16][128];
  const int tid = threadIdx.x;
  const int rl = tid >> 4, sub = tid & 15;
  const int r = blockIdx.x*16 + rl;
  const float2 gv = *(const float2*)(g + r*2);
  {
    const float4 wa0 = ((const float4*)Wf1)[sub*2],       wa1 = ((const float4*)Wf1)[sub*2 + 1];
    const float4 wb0 = ((const float4*)(Wf1+128))[sub*2], wb1 = ((const float4*)(Wf1+128))[sub*2 + 1];
    const float4 bb0 = ((const float4*)bf1)[sub*2],       bb1 = ((const float4*)bf1)[sub*2 + 1];
    float4 a0, a1;
    a0.x = LEAKY(fmaf(gv.x, wa0.x, fmaf(gv.y, wb0.x, bb0.x)));
    a0.y = LEAKY(fmaf(gv.x, wa0.y, fmaf(gv.y, wb0.y, bb0.y)));
    a0.z = LEAKY(fmaf(gv.x, wa0.z, fmaf(gv.y, wb0.z, bb0.z)));
    a0.w = LEAKY(fmaf(gv.x, wa0.w, fmaf(gv.y, wb0.w, bb0.w)));
    a1.x = LEAKY(fmaf(gv.x, wa1.x, fmaf(gv.y, wb1.x, bb1.x)));
    a1.y = LEAKY(fmaf(gv.x, wa1.y, fmaf(gv.y, wb1.y, bb1.y)));
    a1.z = LEAKY(fmaf(gv.x, wa1.z, fmaf(gv.y, wb1.z, bb1.z)));
    a1.w = LEAKY(fmaf(gv.x, wa1.w, fmaf(gv.y, wb1.w, bb1.w)));
    *(float4*)&act[rl][sub*8]     = a0;
    *(float4*)&act[rl][sub*8 + 4] = a1;
  }
  __syncthreads();
  float h2[8];
  {
    const float4 c0 = ((const float4*)bf2)[sub*2], c1 = ((const float4*)bf2)[sub*2 + 1];
    h2[0]=c0.x; h2[1]=c0.y; h2[2]=c0.z; h2[3]=c0.w;
    h2[4]=c1.x; h2[5]=c1.y; h2[6]=c1.z; h2[7]=c1.w;
  }
  #pragma unroll 4
  for (int k = 0; k < 128; ++k) {
    const float a = act[rl][k];
    const float4 w0 = ((const float4*)(Wf2 + k*128))[sub*2];
    const float4 w1 = ((const float4*)(Wf2 + k*128))[sub*2 + 1];
    h2[0] = fmaf(a, w0.x, h2[0]); h2[1] = fmaf(a, w0.y, h2[1]);
    h2[2] = fmaf(a, w0.z, h2[2]); h2[3] = fmaf(a, w0.w, h2[3]);
    h2[4] = fmaf(a, w1.x, h2[4]); h2[5] = fmaf(a, w1.y, h2[5]);
    h2[6] = fmaf(a, w1.z, h2[6]); h2[7] = fmaf(a, w1.w, h2[7]);
  }
  float p0 = 0.f, p1 = 0.f;
  {
    const float4 w3a = ((const float4*)Wf3)[sub*4 + 0];
    const float4 w3b = ((const float4*)Wf3)[sub*4 + 1];
    const float4 w3c = ((const float4*)Wf3)[sub*4 + 2];
    const float4 w3d = ((const float4*)Wf3)[sub*4 + 3];
    const float v0 = LEAKY(h2[0]), v1 = LEAKY(h2[1]), v2 = LEAKY(h2[2]), v3 = LEAKY(h2[3]);
    const float v4 = LEAKY(h2[4]), v5 = LEAKY(h2[5]), v6 = LEAKY(h2[6]), v7 = LEAKY(h2[7]);
    p0 = v0*w3a.x + v1*w3a.z + v2*w3b.x + v3*w3b.z + v4*w3c.x + v5*w3c.z + v6*w3d.x + v7*w3d.z;
    p1 = v0*w3a.y + v1*w3a.w + v2*w3b.y + v3*w3b.w + v4*w3c.y + v5*w3c.w + v6*w3d.y + v7*w3d.w;
  }
  #pragma unroll
  for (int o = 8; o; o >>= 1) { p0 += __shfl_xor(p0, o); p1 += __shfl_xor(p1, o); }
  if (sub == 0) {
    const float s0 = 1.f/(1.f + __expf(-(p0 + bf3[0])));
    const float s1 = 1.f/(1.f + __expf(-(p1 + bf3[1])));
    *(float2*)(out + r*2) = make_float2(s0, s1);
  }
}

extern "C" void kernel_launch(void* const* d_in, const int* in_sizes, int n_in,
                              void* d_out, int out_size, void* d_ws, size_t ws_size,
                              hipStream_t stream) {
  (void)in_sizes; (void)n_in; (void)out_size; (void)ws_size;
  const float* x_ue      = (const float*)d_in[0];
  const float* x_ap      = (const float*)d_in[1];
  const float* edge_attr = (const float*)d_in[2];
  const int*   edge_src  = (const int*)d_in[3];
  const float* Wn1u = (const float*)d_in[5];
  const float* bn1u = (const float*)d_in[6];
  const float* Wn2u = (const float*)d_in[7];
  const float* bn2u = (const float*)d_in[8];
  const float* Wn1a = (const float*)d_in[9];
  const float* bn1a = (const float*)d_in[10];
  const float* Wn2a = (const float*)d_in[11];
  const float* bn2a = (const float*)d_in[12];
  const float* We1  = (const float*)d_in[13];
  const float* be1  = (const float*)d_in[14];
  const float* We2  = (const float*)d_in[15];
  const float* be2  = (const float*)d_in[16];
  const float* strong = (const float*)d_in[17];
  const float* inits  = (const float*)d_in[18];
  const float* update = (const float*)d_in[19];
  const float* Wu1  = (const float*)d_in[20];
  const float* bu1  = (const float*)d_in[21];
  const float* Wu2  = (const float*)d_in[22];
  const float* bu2  = (const float*)d_in[23];
  const float* ln_g = (const float*)d_in[24];
  const float* ln_b = (const float*)d_in[25];
  const float* Wf1  = (const float*)d_in[26];
  const float* bf1  = (const float*)d_in[27];
  const float* Wf2  = (const float*)d_in[28];
  const float* bf2  = (const float*)d_in[29];
  const float* Wf3  = (const float*)d_in[30];
  const float* bf3  = (const float*)d_in[31];

  float* ws = (float*)d_ws;

  setup_kernel<<<65, 256, 0, stream>>>(x_ap, Wn1a, bn1a, Wn2a, bn2a,
                                       strong, inits, update, ws);
  mega_kernel<<<2048, 256, 0, stream>>>(x_ue, edge_attr, edge_src,
                                        Wn1u, bn1u, Wn2u, bn2u,
                                        We1, be1, We2, be2,
                                        ws,
                                        Wu1, bu1, Wu2, bu2, ln_g, ln_b);
  head_kernel<<<512, 256, 0, stream>>>(ws + G_F, Wf1, bf1, Wf2, bf2, Wf3, bf3,
                                       (float*)d_out);
}

// Round 8
// 41.609 us; speedup vs baseline: 1.8087x; 1.1608x over previous
//
#include <hip/hip_runtime.h>

#define LEAKY(x) ((x) > 0.0f ? (x) : 0.01f * (x))

// ws float layout
#define GP_F    672     // GP inside consts [0..2208)
#define APE     2208    // ap_enc 4096
#define UEE     6304    // ue_enc 16384
#define EAE     22688   // ea_enc 49152
#define G_F     71840   // g 16384

__device__ __forceinline__ float2 cmul(float2 a, float2 b) {
  return make_float2(fmaf(a.x, b.x, -a.y * b.y), fmaf(a.x, b.y, a.y * b.x));
}
__device__ __forceinline__ float2 cmulc(float2 a, float2 b) {  // conj(a)*b
  return make_float2(fmaf(a.x, b.x, a.y * b.y), fmaf(a.x, b.y, -a.y * b.x));
}
__device__ __forceinline__ float2 cadd(float2 a, float2 b) {
  return make_float2(a.x + b.x, a.y + b.y);
}
__device__ __forceinline__ float2 csub(float2 a, float2 b) {
  return make_float2(a.x - b.x, a.y - b.y);
}
__device__ __forceinline__ void swap2(float2& a, float2& b) {
  float2 t = a; a = b; b = t;
}

struct C2 { float2 e[4]; };

__device__ C2 cmm(const C2& A, const C2& B) {
  C2 R;
  #pragma unroll
  for (int r = 0; r < 2; ++r)
    #pragma unroll
    for (int c = 0; c < 2; ++c)
      R.e[r*2+c] = cadd(cmul(A.e[r*2+0], B.e[0*2+c]), cmul(A.e[r*2+1], B.e[1*2+c]));
  return R;
}
__device__ C2 gRX(float t) {
  float s = __sinf(0.5f*t), c = __cosf(0.5f*t);
  C2 M;
  M.e[0] = make_float2(c, 0.f);  M.e[1] = make_float2(0.f, -s);
  M.e[2] = make_float2(0.f, -s); M.e[3] = make_float2(c, 0.f);
  return M;
}
__device__ C2 gRY(float t) {
  float s = __sinf(0.5f*t), c = __cosf(0.5f*t);
  C2 M;
  M.e[0] = make_float2(c, 0.f);  M.e[1] = make_float2(-s, 0.f);
  M.e[2] = make_float2(s, 0.f);  M.e[3] = make_float2(c, 0.f);
  return M;
}
__device__ C2 gRZ(float t) {
  float s = __sinf(0.5f*t), c = __cosf(0.5f*t);
  C2 M;
  M.e[0] = make_float2(c, -s);    M.e[1] = make_float2(0.f, 0.f);
  M.e[2] = make_float2(0.f, 0.f); M.e[3] = make_float2(c, s);
  return M;
}
__device__ C2 gROT(float phi, float th, float om) {
  return cmm(cmm(gRZ(om), gRY(th)), gRZ(phi));
}

// row-per-thread 2-layer MLP; W1 transposed in LDS, all reads wave-uniform (broadcast).
template<int D>
__device__ __forceinline__ void encode_block(
    const float* __restrict__ x, int r,
    const float* __restrict__ W1, const float* __restrict__ b1,
    const float* __restrict__ W2, const float* __restrict__ b2,
    float* w1t, float* b1s, float* w2s, float* __restrict__ outp, int tid) {
  #pragma unroll
  for (int i = 0; i < D/2; ++i) {
    const int idx = i*256 + tid;
    const float v = W1[idx];
    w1t[(idx & 127)*D + (idx >> 7)] = v;
  }
  if (tid < 128) b1s[tid] = b1[tid];
  w2s[tid] = W2[tid];
  __syncthreads();

  float xv[D];
  *(float4*)xv = *(const float4*)(x + r*D);
  if (D == 8) *(float4*)(xv + 4) = *(const float4*)(x + r*D + 4);

  float o0 = 0.f, o1 = 0.f;
  #pragma unroll 4
  for (int j = 0; j < 128; ++j) {
    float h = b1s[j];
    #pragma unroll
    for (int k = 0; k < D; k += 4) {
      const float4 w = *(const float4*)&w1t[j*D + k];
      h = fmaf(xv[k],   w.x, h);
      h = fmaf(xv[k+1], w.y, h);
      h = fmaf(xv[k+2], w.z, h);
      h = fmaf(xv[k+3], w.w, h);
    }
    h = LEAKY(h);
    const float2 w2 = *(const float2*)&w2s[j*2];
    o0 = fmaf(h, w2.x, o0);
    o1 = fmaf(h, w2.y, o1);
  }
  *(float2*)(outp + r*2) = make_float2(o0 + b2[0], o1 + b2[1]);
}

// blocks 0..135: encoders (256 rows/block, row-per-thread). block 136: gate algebra.
__global__ __launch_bounds__(256) void enc_kernel(
    const float* __restrict__ x_ue, const float* __restrict__ x_ap,
    const float* __restrict__ edge_attr,
    const float* __restrict__ Wn1u, const float* __restrict__ bn1u,
    const float* __restrict__ Wn2u, const float* __restrict__ bn2u,
    const float* __restrict__ Wn1a, const float* __restrict__ bn1a,
    const float* __restrict__ Wn2a, const float* __restrict__ bn2a,
    const float* __restrict__ We1,  const float* __restrict__ be1,
    const float* __restrict__ We2,  const float* __restrict__ be2,
    const float* __restrict__ strongp, const float* __restrict__ initsp,
    const float* __restrict__ updatep, float* __restrict__ ws) {
  __shared__ __align__(16) float w1t[1024];
  __shared__ float b1s[128];
  __shared__ __align__(8) float w2s[256];
  __shared__ float2 U2s[16][17];
  const int bi = blockIdx.x, tid = threadIdx.x;

  if (bi < 32) {
    encode_block<8>(x_ue, bi*256 + tid, Wn1u, bn1u, Wn2u, bn2u,
                    w1t, b1s, w2s, ws + UEE, tid);
    return;
  } else if (bi < 40) {
    encode_block<8>(x_ap, (bi-32)*256 + tid, Wn1a, bn1a, Wn2a, bn2a,
                    w1t, b1s, w2s, ws + APE, tid);
    return;
  } else if (bi < 136) {
    encode_block<4>(edge_attr, (bi-40)*256 + tid, We1, be1, We2, be2,
                    w1t, b1s, w2s, ws + EAE, tid);
    return;
  }

  // ---- gate algebra (block 136) ----
  if (tid < 48) {
    // U_k (k=tid>>4), column col=tid&15. bit masks: wire3=8, nb=4, w7=2, w8=1.
    const int k = tid >> 4, col = tid & 15;
    float2 u[16];
    #pragma unroll
    for (int r = 0; r < 16; ++r) u[r] = make_float2(r == col ? 1.f : 0.f, 0.f);
    #pragma unroll
    for (int l = 0; l < 2; ++l) {
      #pragma unroll
      for (int j = 0; j < 4; ++j) {
        const float* p = updatep + k*24 + l*12 + j*3;
        C2 U = gROT(p[0], p[1], p[2]);
        const int m = 8 >> j;
        #pragma unroll
        for (int r = 0; r < 16; ++r)
          if (!(r & m)) {
            float2 a0 = u[r], a1 = u[r | m];
            u[r]     = cadd(cmul(U.e[0], a0), cmul(U.e[1], a1));
            u[r | m] = cadd(cmul(U.e[2], a0), cmul(U.e[3], a1));
          }
      }
      #pragma unroll
      for (int j = 0; j < 4; ++j) {
        const int mc = 8 >> j;
        const int mt0[4] = {4, 2, 1, 8};
        const int mt1[4] = {2, 1, 8, 4};
        const int mt = (l == 0) ? mt0[j] : mt1[j];
        #pragma unroll
        for (int r = 0; r < 16; ++r)
          if ((r & mc) && !(r & mt)) swap2(u[r], u[r | mt]);
      }
    }
    if (k == 0) {
      if (!(col & 3)) {
        const int jc = col >> 2;
        #pragma unroll
        for (int r = 0; r < 16; ++r) {
          ws[32 + (jc*16 + r)*2 + 0] = u[r].x;
          ws[32 + (jc*16 + r)*2 + 1] = u[r].y;
        }
      }
    } else if (k == 1) {
      #pragma unroll
      for (int r = 0; r < 16; ++r) {
        ws[160 + (col*16 + r)*2 + 0] = u[r].x;
        ws[160 + (col*16 + r)*2 + 1] = u[r].y;
      }
    } else {
      #pragma unroll
      for (int r = 0; r < 16; ++r) U2s[col][r] = u[r];   // U2s[q][t] = U2[t][q]
    }
  }
  if (tid == 48) {
    // M_edge 4x4 (basis (b_e<<1)|b_nb)
    float2 M[4][4];
    #pragma unroll
    for (int r = 0; r < 4; ++r)
      #pragma unroll
      for (int c = 0; c < 4; ++c)
        M[r][c] = make_float2(r == c ? 1.f : 0.f, 0.f);
    auto rowpair = [&](int r0, int r1, C2 U) {
      #pragma unroll
      for (int c = 0; c < 4; ++c) {
        float2 a0 = M[r0][c], a1 = M[r1][c];
        M[r0][c] = cadd(cmul(U.e[0], a0), cmul(U.e[1], a1));
        M[r1][c] = cadd(cmul(U.e[2], a0), cmul(U.e[3], a1));
      }
    };
    auto rowswap = [&](int r0, int r1) {
      #pragma unroll
      for (int c = 0; c < 4; ++c) swap2(M[r0][c], M[r1][c]);
    };
    rowpair(1, 3, gRX(initsp[0]));
    rowpair(2, 3, gRY(initsp[1]));
    #pragma unroll
    for (int l = 0; l < 2; ++l) {
      C2 Re = gROT(strongp[l*6+0], strongp[l*6+1], strongp[l*6+2]);
      C2 Rn = gROT(strongp[l*6+3], strongp[l*6+4], strongp[l*6+5]);
      rowpair(0, 2, Re); rowpair(1, 3, Re);
      rowpair(0, 1, Rn); rowpair(2, 3, Rn);
      rowswap(2, 3);
      rowswap(1, 3);
    }
    #pragma unroll
    for (int r = 0; r < 4; ++r)
      #pragma unroll
      for (int c = 0; c < 4; ++c) {
        ws[(r*4 + c)*2 + 0] = M[r][c].x;
        ws[(r*4 + c)*2 + 1] = M[r][c].y;
      }
  }
  __syncthreads();
  {
    // GP: 256 threads, one (c,cp,n,np) each, 3 wires.
    const int c = tid >> 5, cp = (tid >> 2) & 7, n = (tid >> 1) & 1, np = tid & 1;
    const int q  = ((c  & 4) << 1) | (n  << 2) | (c  & 3);
    const int qp = ((cp & 4) << 1) | (np << 2) | (cp & 3);
    float2 g3 = make_float2(0,0), g7 = g3, g8 = g3;
    #pragma unroll
    for (int t = 0; t < 16; ++t) {
      float2 pr = cmulc(U2s[q][t], U2s[qp][t]);
      g3 = (t & 8) ? csub(g3, pr) : cadd(g3, pr);
      g7 = (t & 2) ? csub(g7, pr) : cadd(g7, pr);
      g8 = (t & 1) ? csub(g8, pr) : cadd(g8, pr);
    }
    const int idx = (c*2 + n)*16 + (cp*2 + np);
    ws[GP_F + (0*256 + idx)*2 + 0] = g3.x;
    ws[GP_F + (0*256 + idx)*2 + 1] = g3.y;
    ws[GP_F + (1*256 + idx)*2 + 0] = g7.x;
    ws[GP_F + (1*256 + idx)*2 + 1] = g7.y;
    ws[GP_F + (2*256 + idx)*2 + 0] = g8.x;
    ws[GP_F + (2*256 + idx)*2 + 1] = g8.y;
  }
}

// 4 UEs/block (1/wave). Consts staged in LDS; enc values read from ws.
__global__ __launch_bounds__(256) void circuit_kernel(
    float* __restrict__ ws, const int* __restrict__ esrc,
    const float* __restrict__ Wu1, const float* __restrict__ bu1,
    const float* __restrict__ Wu2, const float* __restrict__ bu2,
    const float* __restrict__ lng, const float* __restrict__ lnb) {
  __shared__ __align__(16) float2 cst[1104];   // ME 16 | U0c 64 | U1t 256 | GP 768
  __shared__ __align__(16) float2 pr_s[4][3][4];
  __shared__ __align__(16) float2 psi0[4][2][16];
  __shared__ __align__(16) float2 psi2[4][8][16];
  const int tid = threadIdx.x, wv = tid >> 6, lane = tid & 63;
  const int u = blockIdx.x*4 + wv;

  {
    const float4* s4 = (const float4*)ws;
    float4* d4 = (float4*)cst;
    #pragma unroll
    for (int i = tid; i < 552; i += 256) d4[i] = s4[i];
  }
  __syncthreads();

  const float2* MEl  = cst;
  const float2* U0cl = cst + 16;
  const float2* U1tl = cst + 80;
  const float2* GPl  = cst + 336;

  auto mkv = [](float aa, float bb, float2& v0, float2& v1) {
    const float sa = __sinf(0.5f*aa), ca = __cosf(0.5f*aa);
    const float sb = __sinf(0.5f*bb), cb = __cosf(0.5f*bb);
    v0 = make_float2(cb*ca, -sb*ca);
    v1 = make_float2(sa*sb, -sa*cb);
  };
  const float2 ue_ab = *(const float2*)(ws + UEE + u*2);
  float2 t0, t1;
  mkv(ue_ab.x, ue_ab.y, t0, t1);

  // ---- pairs (lanes 0..11): i = lane>>2, r = lane&3 ----
  if (lane < 12) {
    const int i = lane >> 2, r = lane & 3;
    const float2 eab = *(const float2*)(ws + EAE + (u*3 + i)*2);
    const int s = esrc[u*3 + i];
    const float2 nab = *(const float2*)(ws + APE + s*2);
    float2 e0, e1, n0, n1;
    mkv(eab.x, eab.y, e0, e1);
    mkv(nab.x, nab.y, n0, n1);
    float2 in4[4] = {cmul(e0,n0), cmul(e0,n1), cmul(e1,n0), cmul(e1,n1)};
    float2 acc = make_float2(0.f, 0.f);
    #pragma unroll
    for (int cc = 0; cc < 4; ++cc) acc = cadd(acc, cmul(MEl[r*4 + cc], in4[cc]));
    pr_s[wv][i][r] = acc;
  }

  // ---- block0: psi0 (lanes 0..31) ----
  if (lane < 32) {
    const int b = lane >> 4, row = lane & 15;
    float2 acc = make_float2(0.f, 0.f);
    #pragma unroll
    for (int j = 0; j < 4; ++j) {
      const float2 phi = pr_s[wv][0][(b << 1) | (j & 1)];
      const float2 coef = cmul((j >> 1) ? t1 : t0, phi);
      acc = cadd(acc, cmul(U0cl[j*16 + row], coef));
    }
    psi0[wv][b][row] = acc;
  }

  // ---- block1: psi2 (all lanes, 2 rows each) ----
  {
    const int ibr = lane >> 3, rp = lane & 7;
    const int db = ibr >> 2, da = (ibr >> 1) & 1, dbp = ibr & 1;
    const float2 f10 = pr_s[wv][1][(dbp << 1) | 0];
    const float2 f11 = pr_s[wv][1][(dbp << 1) | 1];
    float2 chi[8];
    {
      const float4 a0 = *(const float4*)&psi0[wv][db][da*4 + 0];
      const float4 a1 = *(const float4*)&psi0[wv][db][da*4 + 2];
      const float4 a2 = *(const float4*)&psi0[wv][db][8 + da*4 + 0];
      const float4 a3 = *(const float4*)&psi0[wv][db][8 + da*4 + 2];
      chi[0] = make_float2(a0.x, a0.y); chi[1] = make_float2(a0.z, a0.w);
      chi[2] = make_float2(a1.x, a1.y); chi[3] = make_float2(a1.z, a1.w);
      chi[4] = make_float2(a2.x, a2.y); chi[5] = make_float2(a2.z, a2.w);
      chi[6] = make_float2(a3.x, a3.y); chi[7] = make_float2(a3.z, a3.w);
    }
    float2 q0 = make_float2(0.f, 0.f), q1 = q0;
    #pragma unroll
    for (int q = 0; q < 16; ++q) {
      const int cc = ((q >> 3) << 2) | (q & 3);
      const float2 xq = cmul(chi[cc], (q & 4) ? f11 : f10);
      q0 = cadd(q0, cmul(U1tl[q*16 + rp],     xq));
      q1 = cadd(q1, cmul(U1tl[q*16 + rp + 8], xq));
    }
    psi2[wv][ibr][rp]     = q0;
    psi2[wv][ibr][rp + 8] = q1;
  }

  // ---- R[c,cp] ----
  const int c = lane >> 3, cp = lane & 7;
  const int mc0 = ((c  & 4) << 1) | (c  & 3);
  const int mp0 = ((cp & 4) << 1) | (cp & 3);
  float2 R = make_float2(0.f, 0.f);
  #pragma unroll
  for (int br = 0; br < 8; ++br) {
    const float2 z10 = psi2[wv][br][mc0], z11 = psi2[wv][br][mc0 + 4];
    const float2 z20 = psi2[wv][br][mp0], z21 = psi2[wv][br][mp0 + 4];
    R.x += z10.x*z20.x + z10.y*z20.y + z11.x*z21.x + z11.y*z21.y;
    R.y += z10.y*z20.x - z10.x*z20.y + z11.y*z21.x - z11.x*z21.y;
  }

  // ---- rho2, K_w, ev ----
  const float4 f2a = *(const float4*)&pr_s[wv][2][0];
  const float4 f2b = *(const float4*)&pr_s[wv][2][2];
  const float2 f20 = make_float2(f2a.x, f2a.y), f21 = make_float2(f2a.z, f2a.w);
  const float2 f22 = make_float2(f2b.x, f2b.y), f23 = make_float2(f2b.z, f2b.w);
  const float2 rho00 = make_float2(f20.x*f20.x + f20.y*f20.y + f22.x*f22.x + f22.y*f22.y, 0.f);
  const float2 rho11 = make_float2(f21.x*f21.x + f21.y*f21.y + f23.x*f23.x + f23.y*f23.y, 0.f);
  const float2 rho01 = make_float2(fmaf(f20.x,f21.x,f20.y*f21.y) + fmaf(f22.x,f23.x,f22.y*f23.y),
                                   (f20.y*f21.x - f20.x*f21.y) + (f22.y*f23.x - f22.x*f23.y));
  const float2 rho10 = make_float2(rho01.x, -rho01.y);

  float ev0, ev1, ev2;
  {
    const int base = (c*2)*16 + (cp*2);
    #pragma unroll
    for (int w = 0; w < 3; ++w) {
      const float2 g00 = GPl[w*256 + base];
      const float2 g01 = GPl[w*256 + base + 1];
      const float2 g10 = GPl[w*256 + base + 16];
      const float2 g11 = GPl[w*256 + base + 17];
      float2 K = cmul(g00, rho00);
      K = cadd(K, cmul(g01, rho10));
      K = cadd(K, cmul(g10, rho01));
      K = cadd(K, cmul(g11, rho11));
      const float e = K.x*R.x + K.y*R.y;
      if (w == 0) ev0 = e; else if (w == 1) ev1 = e; else ev2 = e;
    }
  }
  #pragma unroll
  for (int o = 32; o; o >>= 1) {
    ev0 += __shfl_xor(ev0, o);
    ev1 += __shfl_xor(ev1, o);
    ev2 += __shfl_xor(ev2, o);
  }

  // ---- Wu MLP + residual + LN -> g ----
  const int j1 = lane, j2 = lane + 64;
  const float in5[5] = {ue_ab.x, ue_ab.y, ev0, ev1, ev2};
  float h1 = bu1[j1], h2 = bu1[j2];
  #pragma unroll
  for (int k = 0; k < 5; ++k) {
    h1 = fmaf(in5[k], Wu1[k*128 + j1], h1);
    h2 = fmaf(in5[k], Wu1[k*128 + j2], h2);
  }
  h1 = LEAKY(h1); h2 = LEAKY(h2);
  const float2 wu2a = *(const float2*)(Wu2 + j1*2);
  const float2 wu2b = *(const float2*)(Wu2 + j2*2);
  float p0 = fmaf(h1, wu2a.x, h2*wu2b.x);
  float p1 = fmaf(h1, wu2a.y, h2*wu2b.y);
  #pragma unroll
  for (int o = 32; o; o >>= 1) { p0 += __shfl_xor(p0, o); p1 += __shfl_xor(p1, o); }
  if (lane == 0) {
    const float hh0 = ue_ab.x + p0 + bu2[0];
    const float hh1 = ue_ab.y + p1 + bu2[1];
    const float mu = 0.5f*(hh0 + hh1);
    const float dd = hh0 - mu;
    const float inv = rsqrtf(dd*dd + 1e-5f);
    const float g0 =  dd*inv*lng[0] + lnb[0];
    const float g1 = -dd*inv*lng[1] + lnb[1];
    *(float2*)(ws + G_F + u*2) = make_float2(g0, g1);
  }
}

// head: 16 rows/block, 16 threads/row, 8 cols/thread.
__global__ __launch_bounds__(256) void head_kernel(
    const float* __restrict__ g,
    const float* __restrict__ Wf1, const float* __restrict__ bf1,
    const float* __restrict__ Wf2, const float* __restrict__ bf2,
    const float* __restrict__ Wf3, const float* __restrict__ bf3,
    float* __restrict__ out) {
  __shared__ float act[16][128];
  const int tid = threadIdx.x;
  const int rl = tid >> 4, sub = tid & 15;
  const int r = blockIdx.x*16 + rl;
  const float2 gv = *(const float2*)(g + r*2);
  {
    const float4 wa0 = ((const float4*)Wf1)[sub*2],       wa1 = ((const float4*)Wf1)[sub*2 + 1];
    const float4 wb0 = ((const float4*)(Wf1+128))[sub*2], wb1 = ((const float4*)(Wf1+128))[sub*2 + 1];
    const float4 bb0 = ((const float4*)bf1)[sub*2],       bb1 = ((const float4*)bf1)[sub*2 + 1];
    float4 a0, a1;
    a0.x = LEAKY(fmaf(gv.x, wa0.x, fmaf(gv.y, wb0.x, bb0.x)));
    a0.y = LEAKY(fmaf(gv.x, wa0.y, fmaf(gv.y, wb0.y, bb0.y)));
    a0.z = LEAKY(fmaf(gv.x, wa0.z, fmaf(gv.y, wb0.z, bb0.z)));
    a0.w = LEAKY(fmaf(gv.x, wa0.w, fmaf(gv.y, wb0.w, bb0.w)));
    a1.x = LEAKY(fmaf(gv.x, wa1.x, fmaf(gv.y, wb1.x, bb1.x)));
    a1.y = LEAKY(fmaf(gv.x, wa1.y, fmaf(gv.y, wb1.y, bb1.y)));
    a1.z = LEAKY(fmaf(gv.x, wa1.z, fmaf(gv.y, wb1.z, bb1.z)));
    a1.w = LEAKY(fmaf(gv.x, wa1.w, fmaf(gv.y, wb1.w, bb1.w)));
    *(float4*)&act[rl][sub*8]     = a0;
    *(float4*)&act[rl][sub*8 + 4] = a1;
  }
  __syncthreads();
  float h2[8];
  {
    const float4 c0 = ((const float4*)bf2)[sub*2], c1 = ((const float4*)bf2)[sub*2 + 1];
    h2[0]=c0.x; h2[1]=c0.y; h2[2]=c0.z; h2[3]=c0.w;
    h2[4]=c1.x; h2[5]=c1.y; h2[6]=c1.z; h2[7]=c1.w;
  }
  #pragma unroll 4
  for (int k = 0; k < 128; ++k) {
    const float a = act[rl][k];
    const float4 w0 = ((const float4*)(Wf2 + k*128))[sub*2];
    const float4 w1 = ((const float4*)(Wf2 + k*128))[sub*2 + 1];
    h2[0] = fmaf(a, w0.x, h2[0]); h2[1] = fmaf(a, w0.y, h2[1]);
    h2[2] = fmaf(a, w0.z, h2[2]); h2[3] = fmaf(a, w0.w, h2[3]);
    h2[4] = fmaf(a, w1.x, h2[4]); h2[5] = fmaf(a, w1.y, h2[5]);
    h2[6] = fmaf(a, w1.z, h2[6]); h2[7] = fmaf(a, w1.w, h2[7]);
  }
  float p0 = 0.f, p1 = 0.f;
  {
    const float4 w3a = ((const float4*)Wf3)[sub*4 + 0];
    const float4 w3b = ((const float4*)Wf3)[sub*4 + 1];
    const float4 w3c = ((const float4*)Wf3)[sub*4 + 2];
    const float4 w3d = ((const float4*)Wf3)[sub*4 + 3];
    const float v0 = LEAKY(h2[0]), v1 = LEAKY(h2[1]), v2 = LEAKY(h2[2]), v3 = LEAKY(h2[3]);
    const float v4 = LEAKY(h2[4]), v5 = LEAKY(h2[5]), v6 = LEAKY(h2[6]), v7 = LEAKY(h2[7]);
    p0 = v0*w3a.x + v1*w3a.z + v2*w3b.x + v3*w3b.z + v4*w3c.x + v5*w3c.z + v6*w3d.x + v7*w3d.z;
    p1 = v0*w3a.y + v1*w3a.w + v2*w3b.y + v3*w3b.w + v4*w3c.y + v5*w3c.w + v6*w3d.y + v7*w3d.w;
  }
  #pragma unroll
  for (int o = 8; o; o >>= 1) { p0 += __shfl_xor(p0, o); p1 += __shfl_xor(p1, o); }
  if (sub == 0) {
    const float s0 = 1.f/(1.f + __expf(-(p0 + bf3[0])));
    const float s1 = 1.f/(1.f + __expf(-(p1 + bf3[1])));
    *(float2*)(out + r*2) = make_float2(s0, s1);
  }
}

extern "C" void kernel_launch(void* const* d_in, const int* in_sizes, int n_in,
                              void* d_out, int out_size, void* d_ws, size_t ws_size,
                              hipStream_t stream) {
  (void)in_sizes; (void)n_in; (void)out_size; (void)ws_size;
  const float* x_ue      = (const float*)d_in[0];
  const float* x_ap      = (const float*)d_in[1];
  const float* edge_attr = (const float*)d_in[2];
  const int*   edge_src  = (const int*)d_in[3];
  const float* Wn1u = (const float*)d_in[5];
  const float* bn1u = (const float*)d_in[6];
  const float* Wn2u = (const float*)d_in[7];
  const float* bn2u = (const float*)d_in[8];
  const float* Wn1a = (const float*)d_in[9];
  const float* bn1a = (const float*)d_in[10];
  const float* Wn2a = (const float*)d_in[11];
  const float* bn2a = (const float*)d_in[12];
  const float* We1  = (const float*)d_in[13];
  const float* be1  = (const float*)d_in[14];
  const float* We2  = (const float*)d_in[15];
  const float* be2  = (const float*)d_in[16];
  const float* strong = (const float*)d_in[17];
  const float* inits  = (const float*)d_in[18];
  const float* update = (const float*)d_in[19];
  const float* Wu1  = (const float*)d_in[20];
  const float* bu1  = (const float*)d_in[21];
  const float* Wu2  = (const float*)d_in[22];
  const float* bu2  = (const float*)d_in[23];
  const float* ln_g = (const float*)d_in[24];
  const float* ln_b = (const float*)d_in[25];
  const float* Wf1  = (const float*)d_in[26];
  const float* bf1  = (const float*)d_in[27];
  const float* Wf2  = (const float*)d_in[28];
  const float* bf2  = (const float*)d_in[29];
  const float* Wf3  = (const float*)d_in[30];
  const float* bf3  = (const float*)d_in[31];

  float* ws = (float*)d_ws;

  enc_kernel<<<137, 256, 0, stream>>>(x_ue, x_ap, edge_attr,
                                      Wn1u, bn1u, Wn2u, bn2u,
                                      Wn1a, bn1a, Wn2a, bn2a,
                                      We1, be1, We2, be2,
                                      strong, inits, update, ws);
  circuit_kernel<<<2048, 256, 0, stream>>>(ws, edge_src,
                                           Wu1, bu1, Wu2, bu2, ln_g, ln_b);
  head_kernel<<<512, 256, 0, stream>>>(ws + G_F, Wf1, bf1, Wf2, bf2, Wf3, bf3,
                                       (float*)d_out);
}

// Round 9
// 37.987 us; speedup vs baseline: 1.9812x; 1.0953x over previous
//
#include <hip/hip_runtime.h>

#define LEAKY(x) ((x) > 0.0f ? (x) : 0.01f * (x))

// ws float layout
#define GP_F    672     // GP inside consts [0..2208)
#define APE     2208    // ap_enc 4096
#define UEE     6304    // ue_enc 16384
#define EAE     22688   // ea_enc 49152
#define G_F     71840   // g 16384

__device__ __forceinline__ float2 cmul(float2 a, float2 b) {
  return make_float2(fmaf(a.x, b.x, -a.y * b.y), fmaf(a.x, b.y, a.y * b.x));
}
__device__ __forceinline__ float2 cmulc(float2 a, float2 b) {  // conj(a)*b
  return make_float2(fmaf(a.x, b.x, a.y * b.y), fmaf(a.x, b.y, -a.y * b.x));
}
__device__ __forceinline__ float2 cadd(float2 a, float2 b) {
  return make_float2(a.x + b.x, a.y + b.y);
}
__device__ __forceinline__ float2 csub(float2 a, float2 b) {
  return make_float2(a.x - b.x, a.y - b.y);
}
__device__ __forceinline__ void swap2(float2& a, float2& b) {
  float2 t = a; a = b; b = t;
}

struct C2 { float2 e[4]; };

__device__ C2 cmm(const C2& A, const C2& B) {
  C2 R;
  #pragma unroll
  for (int r = 0; r < 2; ++r)
    #pragma unroll
    for (int c = 0; c < 2; ++c)
      R.e[r*2+c] = cadd(cmul(A.e[r*2+0], B.e[0*2+c]), cmul(A.e[r*2+1], B.e[1*2+c]));
  return R;
}
__device__ C2 gRX(float t) {
  float s = __sinf(0.5f*t), c = __cosf(0.5f*t);
  C2 M;
  M.e[0] = make_float2(c, 0.f);  M.e[1] = make_float2(0.f, -s);
  M.e[2] = make_float2(0.f, -s); M.e[3] = make_float2(c, 0.f);
  return M;
}
__device__ C2 gRY(float t) {
  float s = __sinf(0.5f*t), c = __cosf(0.5f*t);
  C2 M;
  M.e[0] = make_float2(c, 0.f);  M.e[1] = make_float2(-s, 0.f);
  M.e[2] = make_float2(s, 0.f);  M.e[3] = make_float2(c, 0.f);
  return M;
}
__device__ C2 gRZ(float t) {
  float s = __sinf(0.5f*t), c = __cosf(0.5f*t);
  C2 M;
  M.e[0] = make_float2(c, -s);    M.e[1] = make_float2(0.f, 0.f);
  M.e[2] = make_float2(0.f, 0.f); M.e[3] = make_float2(c, s);
  return M;
}
__device__ C2 gROT(float phi, float th, float om) {
  return cmm(cmm(gRZ(om), gRY(th)), gRZ(phi));
}

// row-per-thread 2-layer MLP; W1 transposed in LDS, all reads wave-uniform (broadcast).
template<int D>
__device__ __forceinline__ void encode_block(
    const float* __restrict__ x, int r,
    const float* __restrict__ W1, const float* __restrict__ b1,
    const float* __restrict__ W2, const float* __restrict__ b2,
    float* w1t, float* b1s, float* w2s, float* __restrict__ outp, int tid) {
  #pragma unroll
  for (int i = 0; i < D/2; ++i) {
    const int idx = i*256 + tid;
    const float v = W1[idx];
    w1t[(idx & 127)*D + (idx >> 7)] = v;
  }
  if (tid < 128) b1s[tid] = b1[tid];
  w2s[tid] = W2[tid];
  __syncthreads();

  float xv[D];
  *(float4*)xv = *(const float4*)(x + r*D);
  if (D == 8) *(float4*)(xv + 4) = *(const float4*)(x + r*D + 4);

  float o0 = 0.f, o1 = 0.f;
  #pragma unroll 4
  for (int j = 0; j < 128; ++j) {
    float h = b1s[j];
    #pragma unroll
    for (int k = 0; k < D; k += 4) {
      const float4 w = *(const float4*)&w1t[j*D + k];
      h = fmaf(xv[k],   w.x, h);
      h = fmaf(xv[k+1], w.y, h);
      h = fmaf(xv[k+2], w.z, h);
      h = fmaf(xv[k+3], w.w, h);
    }
    h = LEAKY(h);
    const float2 w2 = *(const float2*)&w2s[j*2];
    o0 = fmaf(h, w2.x, o0);
    o1 = fmaf(h, w2.y, o1);
  }
  *(float2*)(outp + r*2) = make_float2(o0 + b2[0], o1 + b2[1]);
}

// blocks 0..135: encoders (256 rows/block, row-per-thread). block 136: gate algebra.
__global__ __launch_bounds__(256) void enc_kernel(
    const float* __restrict__ x_ue, const float* __restrict__ x_ap,
    const float* __restrict__ edge_attr,
    const float* __restrict__ Wn1u, const float* __restrict__ bn1u,
    const float* __restrict__ Wn2u, const float* __restrict__ bn2u,
    const float* __restrict__ Wn1a, const float* __restrict__ bn1a,
    const float* __restrict__ Wn2a, const float* __restrict__ bn2a,
    const float* __restrict__ We1,  const float* __restrict__ be1,
    const float* __restrict__ We2,  const float* __restrict__ be2,
    const float* __restrict__ strongp, const float* __restrict__ initsp,
    const float* __restrict__ updatep, float* __restrict__ ws) {
  __shared__ __align__(16) float w1t[1024];
  __shared__ float b1s[128];
  __shared__ __align__(8) float w2s[256];
  __shared__ float2 U2s[16][17];
  const int bi = blockIdx.x, tid = threadIdx.x;

  if (bi < 32) {
    encode_block<8>(x_ue, bi*256 + tid, Wn1u, bn1u, Wn2u, bn2u,
                    w1t, b1s, w2s, ws + UEE, tid);
    return;
  } else if (bi < 40) {
    encode_block<8>(x_ap, (bi-32)*256 + tid, Wn1a, bn1a, Wn2a, bn2a,
                    w1t, b1s, w2s, ws + APE, tid);
    return;
  } else if (bi < 136) {
    encode_block<4>(edge_attr, (bi-40)*256 + tid, We1, be1, We2, be2,
                    w1t, b1s, w2s, ws + EAE, tid);
    return;
  }

  // ---- gate algebra (block 136) ----
  if (tid < 48) {
    // U_k (k=tid>>4), column col=tid&15. bit masks: wire3=8, nb=4, w7=2, w8=1.
    const int k = tid >> 4, col = tid & 15;
    float2 u[16];
    #pragma unroll
    for (int r = 0; r < 16; ++r) u[r] = make_float2(r == col ? 1.f : 0.f, 0.f);
    #pragma unroll
    for (int l = 0; l < 2; ++l) {
      #pragma unroll
      for (int j = 0; j < 4; ++j) {
        const float* p = updatep + k*24 + l*12 + j*3;
        C2 U = gROT(p[0], p[1], p[2]);
        const int m = 8 >> j;
        #pragma unroll
        for (int r = 0; r < 16; ++r)
          if (!(r & m)) {
            float2 a0 = u[r], a1 = u[r | m];
            u[r]     = cadd(cmul(U.e[0], a0), cmul(U.e[1], a1));
            u[r | m] = cadd(cmul(U.e[2], a0), cmul(U.e[3], a1));
          }
      }
      #pragma unroll
      for (int j = 0; j < 4; ++j) {
        const int mc = 8 >> j;
        const int mt0[4] = {4, 2, 1, 8};
        const int mt1[4] = {2, 1, 8, 4};
        const int mt = (l == 0) ? mt0[j] : mt1[j];
        #pragma unroll
        for (int r = 0; r < 16; ++r)
          if ((r & mc) && !(r & mt)) swap2(u[r], u[r | mt]);
      }
    }
    if (k == 0) {
      if (!(col & 3)) {
        const int jc = col >> 2;
        #pragma unroll
        for (int r = 0; r < 16; ++r) {
          ws[32 + (jc*16 + r)*2 + 0] = u[r].x;
          ws[32 + (jc*16 + r)*2 + 1] = u[r].y;
        }
      }
    } else if (k == 1) {
      #pragma unroll
      for (int r = 0; r < 16; ++r) {
        ws[160 + (col*16 + r)*2 + 0] = u[r].x;
        ws[160 + (col*16 + r)*2 + 1] = u[r].y;
      }
    } else {
      #pragma unroll
      for (int r = 0; r < 16; ++r) U2s[col][r] = u[r];   // U2s[q][t] = U2[t][q]
    }
  }
  if (tid == 48) {
    // M_edge 4x4 (basis (b_e<<1)|b_nb)
    float2 M[4][4];
    #pragma unroll
    for (int r = 0; r < 4; ++r)
      #pragma unroll
      for (int c = 0; c < 4; ++c)
        M[r][c] = make_float2(r == c ? 1.f : 0.f, 0.f);
    auto rowpair = [&](int r0, int r1, C2 U) {
      #pragma unroll
      for (int c = 0; c < 4; ++c) {
        float2 a0 = M[r0][c], a1 = M[r1][c];
        M[r0][c] = cadd(cmul(U.e[0], a0), cmul(U.e[1], a1));
        M[r1][c] = cadd(cmul(U.e[2], a0), cmul(U.e[3], a1));
      }
    };
    auto rowswap = [&](int r0, int r1) {
      #pragma unroll
      for (int c = 0; c < 4; ++c) swap2(M[r0][c], M[r1][c]);
    };
    rowpair(1, 3, gRX(initsp[0]));
    rowpair(2, 3, gRY(initsp[1]));
    #pragma unroll
    for (int l = 0; l < 2; ++l) {
      C2 Re = gROT(strongp[l*6+0], strongp[l*6+1], strongp[l*6+2]);
      C2 Rn = gROT(strongp[l*6+3], strongp[l*6+4], strongp[l*6+5]);
      rowpair(0, 2, Re); rowpair(1, 3, Re);
      rowpair(0, 1, Rn); rowpair(2, 3, Rn);
      rowswap(2, 3);
      rowswap(1, 3);
    }
    #pragma unroll
    for (int r = 0; r < 4; ++r)
      #pragma unroll
      for (int c = 0; c < 4; ++c) {
        ws[(r*4 + c)*2 + 0] = M[r][c].x;
        ws[(r*4 + c)*2 + 1] = M[r][c].y;
      }
  }
  __syncthreads();
  {
    // GP: 256 threads, one (c,cp,n,np) each, 3 wires.
    const int c = tid >> 5, cp = (tid >> 2) & 7, n = (tid >> 1) & 1, np = tid & 1;
    const int q  = ((c  & 4) << 1) | (n  << 2) | (c  & 3);
    const int qp = ((cp & 4) << 1) | (np << 2) | (cp & 3);
    float2 g3 = make_float2(0,0), g7 = g3, g8 = g3;
    #pragma unroll
    for (int t = 0; t < 16; ++t) {
      float2 pr = cmulc(U2s[q][t], U2s[qp][t]);
      g3 = (t & 8) ? csub(g3, pr) : cadd(g3, pr);
      g7 = (t & 2) ? csub(g7, pr) : cadd(g7, pr);
      g8 = (t & 1) ? csub(g8, pr) : cadd(g8, pr);
    }
    const int idx = (c*2 + n)*16 + (cp*2 + np);
    ws[GP_F + (0*256 + idx)*2 + 0] = g3.x;
    ws[GP_F + (0*256 + idx)*2 + 1] = g3.y;
    ws[GP_F + (1*256 + idx)*2 + 0] = g7.x;
    ws[GP_F + (1*256 + idx)*2 + 1] = g7.y;
    ws[GP_F + (2*256 + idx)*2 + 0] = g8.x;
    ws[GP_F + (2*256 + idx)*2 + 1] = g8.y;
  }
}

// 4 UEs/block (1/wave). Consts staged in LDS; enc values read from ws.
__global__ __launch_bounds__(256) void circuit_kernel(
    float* __restrict__ ws, const int* __restrict__ esrc,
    const float* __restrict__ Wu1, const float* __restrict__ bu1,
    const float* __restrict__ Wu2, const float* __restrict__ bu2,
    const float* __restrict__ lng, const float* __restrict__ lnb) {
  __shared__ __align__(16) float2 cst[1104];   // ME 16 | U0c 64 | U1t 256 | GP 768
  __shared__ __align__(16) float2 pr_s[4][3][4];
  __shared__ __align__(16) float2 psi0[4][2][16];
  __shared__ __align__(16) float2 psi2[4][8][16];
  const int tid = threadIdx.x, wv = tid >> 6, lane = tid & 63;
  const int u = blockIdx.x*4 + wv;

  {
    const float4* s4 = (const float4*)ws;
    float4* d4 = (float4*)cst;
    #pragma unroll
    for (int i = tid; i < 552; i += 256) d4[i] = s4[i];
  }
  __syncthreads();

  const float2* MEl  = cst;
  const float2* U0cl = cst + 16;
  const float2* U1tl = cst + 80;
  const float2* GPl  = cst + 336;

  auto mkv = [](float aa, float bb, float2& v0, float2& v1) {
    const float sa = __sinf(0.5f*aa), ca = __cosf(0.5f*aa);
    const float sb = __sinf(0.5f*bb), cb = __cosf(0.5f*bb);
    v0 = make_float2(cb*ca, -sb*ca);
    v1 = make_float2(sa*sb, -sa*cb);
  };
  const float2 ue_ab = *(const float2*)(ws + UEE + u*2);
  float2 t0, t1;
  mkv(ue_ab.x, ue_ab.y, t0, t1);

  // ---- pairs (lanes 0..11): i = lane>>2, r = lane&3 ----
  if (lane < 12) {
    const int i = lane >> 2, r = lane & 3;
    const float2 eab = *(const float2*)(ws + EAE + (u*3 + i)*2);
    const int s = esrc[u*3 + i];
    const float2 nab = *(const float2*)(ws + APE + s*2);
    float2 e0, e1, n0, n1;
    mkv(eab.x, eab.y, e0, e1);
    mkv(nab.x, nab.y, n0, n1);
    float2 in4[4] = {cmul(e0,n0), cmul(e0,n1), cmul(e1,n0), cmul(e1,n1)};
    float2 acc = make_float2(0.f, 0.f);
    #pragma unroll
    for (int cc = 0; cc < 4; ++cc) acc = cadd(acc, cmul(MEl[r*4 + cc], in4[cc]));
    pr_s[wv][i][r] = acc;
  }

  // ---- block0: psi0 (lanes 0..31) ----
  if (lane < 32) {
    const int b = lane >> 4, row = lane & 15;
    float2 acc = make_float2(0.f, 0.f);
    #pragma unroll
    for (int j = 0; j < 4; ++j) {
      const float2 phi = pr_s[wv][0][(b << 1) | (j & 1)];
      const float2 coef = cmul((j >> 1) ? t1 : t0, phi);
      acc = cadd(acc, cmul(U0cl[j*16 + row], coef));
    }
    psi0[wv][b][row] = acc;
  }

  // ---- block1: psi2 (all lanes, 2 rows each) ----
  {
    const int ibr = lane >> 3, rp = lane & 7;
    const int db = ibr >> 2, da = (ibr >> 1) & 1, dbp = ibr & 1;
    const float2 f10 = pr_s[wv][1][(dbp << 1) | 0];
    const float2 f11 = pr_s[wv][1][(dbp << 1) | 1];
    float2 chi[8];
    {
      const float4 a0 = *(const float4*)&psi0[wv][db][da*4 + 0];
      const float4 a1 = *(const float4*)&psi0[wv][db][da*4 + 2];
      const float4 a2 = *(const float4*)&psi0[wv][db][8 + da*4 + 0];
      const float4 a3 = *(const float4*)&psi0[wv][db][8 + da*4 + 2];
      chi[0] = make_float2(a0.x, a0.y); chi[1] = make_float2(a0.z, a0.w);
      chi[2] = make_float2(a1.x, a1.y); chi[3] = make_float2(a1.z, a1.w);
      chi[4] = make_float2(a2.x, a2.y); chi[5] = make_float2(a2.z, a2.w);
      chi[6] = make_float2(a3.x, a3.y); chi[7] = make_float2(a3.z, a3.w);
    }
    float2 q0 = make_float2(0.f, 0.f), q1 = q0;
    #pragma unroll
    for (int q = 0; q < 16; ++q) {
      const int cc = ((q >> 3) << 2) | (q & 3);
      const float2 xq = cmul(chi[cc], (q & 4) ? f11 : f10);
      q0 = cadd(q0, cmul(U1tl[q*16 + rp],     xq));
      q1 = cadd(q1, cmul(U1tl[q*16 + rp + 8], xq));
    }
    psi2[wv][ibr][rp]     = q0;
    psi2[wv][ibr][rp + 8] = q1;
  }

  // ---- R[c,cp] ----
  const int c = lane >> 3, cp = lane & 7;
  const int mc0 = ((c  & 4) << 1) | (c  & 3);
  const int mp0 = ((cp & 4) << 1) | (cp & 3);
  float2 R = make_float2(0.f, 0.f);
  #pragma unroll
  for (int br = 0; br < 8; ++br) {
    const float2 z10 = psi2[wv][br][mc0], z11 = psi2[wv][br][mc0 + 4];
    const float2 z20 = psi2[wv][br][mp0], z21 = psi2[wv][br][mp0 + 4];
    R.x += z10.x*z20.x + z10.y*z20.y + z11.x*z21.x + z11.y*z21.y;
    R.y += z10.y*z20.x - z10.x*z20.y + z11.y*z21.x - z11.x*z21.y;
  }

  // ---- rho2, K_w, ev ----
  const float4 f2a = *(const float4*)&pr_s[wv][2][0];
  const float4 f2b = *(const float4*)&pr_s[wv][2][2];
  const float2 f20 = make_float2(f2a.x, f2a.y), f21 = make_float2(f2a.z, f2a.w);
  const float2 f22 = make_float2(f2b.x, f2b.y), f23 = make_float2(f2b.z, f2b.w);
  const float2 rho00 = make_float2(f20.x*f20.x + f20.y*f20.y + f22.x*f22.x + f22.y*f22.y, 0.f);
  const float2 rho11 = make_float2(f21.x*f21.x + f21.y*f21.y + f23.x*f23.x + f23.y*f23.y, 0.f);
  const float2 rho01 = make_float2(fmaf(f20.x,f21.x,f20.y*f21.y) + fmaf(f22.x,f23.x,f22.y*f23.y),
                                   (f20.y*f21.x - f20.x*f21.y) + (f22.y*f23.x - f22.x*f23.y));
  const float2 rho10 = make_float2(rho01.x, -rho01.y);

  float ev0, ev1, ev2;
  {
    const int base = (c*2)*16 + (cp*2);
    #pragma unroll
    for (int w = 0; w < 3; ++w) {
      const float2 g00 = GPl[w*256 + base];
      const float2 g01 = GPl[w*256 + base + 1];
      const float2 g10 = GPl[w*256 + base + 16];
      const float2 g11 = GPl[w*256 + base + 17];
      float2 K = cmul(g00, rho00);
      K = cadd(K, cmul(g01, rho10));
      K = cadd(K, cmul(g10, rho01));
      K = cadd(K, cmul(g11, rho11));
      const float e = K.x*R.x + K.y*R.y;
      if (w == 0) ev0 = e; else if (w == 1) ev1 = e; else ev2 = e;
    }
  }
  #pragma unroll
  for (int o = 32; o; o >>= 1) {
    ev0 += __shfl_xor(ev0, o);
    ev1 += __shfl_xor(ev1, o);
    ev2 += __shfl_xor(ev2, o);
  }

  // ---- Wu MLP + residual + LN -> g ----
  const int j1 = lane, j2 = lane + 64;
  const float in5[5] = {ue_ab.x, ue_ab.y, ev0, ev1, ev2};
  float h1 = bu1[j1], h2 = bu1[j2];
  #pragma unroll
  for (int k = 0; k < 5; ++k) {
    h1 = fmaf(in5[k], Wu1[k*128 + j1], h1);
    h2 = fmaf(in5[k], Wu1[k*128 + j2], h2);
  }
  h1 = LEAKY(h1); h2 = LEAKY(h2);
  const float2 wu2a = *(const float2*)(Wu2 + j1*2);
  const float2 wu2b = *(const float2*)(Wu2 + j2*2);
  float p0 = fmaf(h1, wu2a.x, h2*wu2b.x);
  float p1 = fmaf(h1, wu2a.y, h2*wu2b.y);
  #pragma unroll
  for (int o = 32; o; o >>= 1) { p0 += __shfl_xor(p0, o); p1 += __shfl_xor(p1, o); }
  if (lane == 0) {
    const float hh0 = ue_ab.x + p0 + bu2[0];
    const float hh1 = ue_ab.y + p1 + bu2[1];
    const float mu = 0.5f*(hh0 + hh1);
    const float dd = hh0 - mu;
    const float inv = rsqrtf(dd*dd + 1e-5f);
    const float g0 =  dd*inv*lng[0] + lnb[0];
    const float g1 = -dd*inv*lng[1] + lnb[1];
    *(float2*)(ws + G_F + u*2) = make_float2(g0, g1);
  }
}

// head GEMM: 64 rows/block, thread tile 4 rows x 8 cols, act transposed in LDS.
__global__ __launch_bounds__(256) void head_kernel(
    const float* __restrict__ g,
    const float* __restrict__ Wf1, const float* __restrict__ bf1,
    const float* __restrict__ Wf2, const float* __restrict__ bf2,
    const float* __restrict__ Wf3, const float* __restrict__ bf3,
    float* __restrict__ out) {
  __shared__ __align__(16) float act_t[128][64];   // [j][row], 32 KB
  const int tid = threadIdx.x;
  const int r0 = blockIdx.x * 64;
  const int wv = tid >> 6;

  // ---- phase 1: act_t[j][row] = leaky(g@Wf1 + bf1), j = p*4 + wv, row = tid&63
  {
    const int row = tid & 63;
    const float2 gv = *(const float2*)(g + (r0 + row)*2);
    #pragma unroll
    for (int p = 0; p < 32; ++p) {
      const int j = p*4 + wv;
      act_t[j][row] = LEAKY(fmaf(gv.x, Wf1[j], fmaf(gv.y, Wf1[128 + j], bf1[j])));
    }
  }
  __syncthreads();

  // ---- phase 2: GEMM. cg = tid&15 (8 cols each), rg = tid>>4 (4 rows each).
  const int cg = tid & 15, rg = tid >> 4;
  float acc[4][8];
  {
    const float4 b0 = *(const float4*)(bf2 + cg*8);
    const float4 b1 = *(const float4*)(bf2 + cg*8 + 4);
    #pragma unroll
    for (int r = 0; r < 4; ++r) {
      acc[r][0]=b0.x; acc[r][1]=b0.y; acc[r][2]=b0.z; acc[r][3]=b0.w;
      acc[r][4]=b1.x; acc[r][5]=b1.y; acc[r][6]=b1.z; acc[r][7]=b1.w;
    }
  }
  #pragma unroll 4
  for (int k = 0; k < 128; ++k) {
    const float4 a4 = *(const float4*)&act_t[k][rg*4];
    const float4 w0 = *(const float4*)(Wf2 + k*128 + cg*8);
    const float4 w1 = *(const float4*)(Wf2 + k*128 + cg*8 + 4);
    const float av[4] = {a4.x, a4.y, a4.z, a4.w};
    #pragma unroll
    for (int r = 0; r < 4; ++r) {
      acc[r][0] = fmaf(av[r], w0.x, acc[r][0]);
      acc[r][1] = fmaf(av[r], w0.y, acc[r][1]);
      acc[r][2] = fmaf(av[r], w0.z, acc[r][2]);
      acc[r][3] = fmaf(av[r], w0.w, acc[r][3]);
      acc[r][4] = fmaf(av[r], w1.x, acc[r][4]);
      acc[r][5] = fmaf(av[r], w1.y, acc[r][5]);
      acc[r][6] = fmaf(av[r], w1.z, acc[r][6]);
      acc[r][7] = fmaf(av[r], w1.w, acc[r][7]);
    }
  }

  // ---- epilogue: leaky, @Wf3, reduce over cg, sigmoid
  float w3x[8], w3y[8];
  #pragma unroll
  for (int c = 0; c < 8; ++c) {
    const float2 w3 = *(const float2*)(Wf3 + (cg*8 + c)*2);
    w3x[c] = w3.x; w3y[c] = w3.y;
  }
  float p0[4], p1[4];
  #pragma unroll
  for (int r = 0; r < 4; ++r) {
    float s0 = 0.f, s1 = 0.f;
    #pragma unroll
    for (int c = 0; c < 8; ++c) {
      const float v = LEAKY(acc[r][c]);
      s0 = fmaf(v, w3x[c], s0);
      s1 = fmaf(v, w3y[c], s1);
    }
    p0[r] = s0; p1[r] = s1;
  }
  #pragma unroll
  for (int o = 8; o; o >>= 1) {
    #pragma unroll
    for (int r = 0; r < 4; ++r) {
      p0[r] += __shfl_xor(p0[r], o);
      p1[r] += __shfl_xor(p1[r], o);
    }
  }
  if (cg == 0) {
    #pragma unroll
    for (int r = 0; r < 4; ++r) {
      const int row = r0 + rg*4 + r;
      const float s0 = 1.f/(1.f + __expf(-(p0[r] + bf3[0])));
      const float s1 = 1.f/(1.f + __expf(-(p1[r] + bf3[1])));
      *(float2*)(out + row*2) = make_float2(s0, s1);
    }
  }
}

extern "C" void kernel_launch(void* const* d_in, const int* in_sizes, int n_in,
                              void* d_out, int out_size, void* d_ws, size_t ws_size,
                              hipStream_t stream) {
  (void)in_sizes; (void)n_in; (void)out_size; (void)ws_size;
  const float* x_ue      = (const float*)d_in[0];
  const float* x_ap      = (const float*)d_in[1];
  const float* edge_attr = (const float*)d_in[2];
  const int*   edge_src  = (const int*)d_in[3];
  const float* Wn1u = (const float*)d_in[5];
  const float* bn1u = (const float*)d_in[6];
  const float* Wn2u = (const float*)d_in[7];
  const float* bn2u = (const float*)d_in[8];
  const float* Wn1a = (const float*)d_in[9];
  const float* bn1a = (const float*)d_in[10];
  const float* Wn2a = (const float*)d_in[11];
  const float* bn2a = (const float*)d_in[12];
  const float* We1  = (const float*)d_in[13];
  const float* be1  = (const float*)d_in[14];
  const float* We2  = (const float*)d_in[15];
  const float* be2  = (const float*)d_in[16];
  const float* strong = (const float*)d_in[17];
  const float* inits  = (const float*)d_in[18];
  const float* update = (const float*)d_in[19];
  const float* Wu1  = (const float*)d_in[20];
  const float* bu1  = (const float*)d_in[21];
  const float* Wu2  = (const float*)d_in[22];
  const float* bu2  = (const float*)d_in[23];
  const float* ln_g = (const float*)d_in[24];
  const float* ln_b = (const float*)d_in[25];
  const float* Wf1  = (const float*)d_in[26];
  const float* bf1  = (const float*)d_in[27];
  const float* Wf2  = (const float*)d_in[28];
  const float* bf2  = (const float*)d_in[29];
  const float* Wf3  = (const float*)d_in[30];
  const float* bf3  = (const float*)d_in[31];

  float* ws = (float*)d_ws;

  enc_kernel<<<137, 256, 0, stream>>>(x_ue, x_ap, edge_attr,
                                      Wn1u, bn1u, Wn2u, bn2u,
                                      Wn1a, bn1a, Wn2a, bn2a,
                                      We1, be1, We2, be2,
                                      strong, inits, update, ws);
  circuit_kernel<<<2048, 256, 0, stream>>>(ws, edge_src,
                                           Wu1, bu1, Wu2, bu2, ln_g, ln_b);
  head_kernel<<<128, 256, 0, stream>>>(ws + G_F, Wf1, bf1, Wf2, bf2, Wf3, bf3,
                                       (float*)d_out);
}

// Round 10
// 37.292 us; speedup vs baseline: 2.0182x; 1.0187x over previous
//
#include <hip/hip_runtime.h>

#define LEAKY(x) ((x) > 0.0f ? (x) : 0.01f * (x))

// ws float layout
#define GP_F    672     // GP inside consts [0..2208)
#define APE     2208    // ap_enc 4096
#define UEE     6304    // ue_enc 16384
#define EAE     22688   // ea_enc 49152
#define G_F     71840   // g 16384

__device__ __forceinline__ float2 cmul(float2 a, float2 b) {
  return make_float2(fmaf(a.x, b.x, -a.y * b.y), fmaf(a.x, b.y, a.y * b.x));
}
__device__ __forceinline__ float2 cmulc(float2 a, float2 b) {  // conj(a)*b
  return make_float2(fmaf(a.x, b.x, a.y * b.y), fmaf(a.x, b.y, -a.y * b.x));
}
__device__ __forceinline__ float2 cadd(float2 a, float2 b) {
  return make_float2(a.x + b.x, a.y + b.y);
}
__device__ __forceinline__ float2 csub(float2 a, float2 b) {
  return make_float2(a.x - b.x, a.y - b.y);
}
__device__ __forceinline__ void swap2(float2& a, float2& b) {
  float2 t = a; a = b; b = t;
}

struct C2 { float2 e[4]; };

__device__ C2 cmm(const C2& A, const C2& B) {
  C2 R;
  #pragma unroll
  for (int r = 0; r < 2; ++r)
    #pragma unroll
    for (int c = 0; c < 2; ++c)
      R.e[r*2+c] = cadd(cmul(A.e[r*2+0], B.e[0*2+c]), cmul(A.e[r*2+1], B.e[1*2+c]));
  return R;
}
__device__ C2 gRX(float t) {
  float s = __sinf(0.5f*t), c = __cosf(0.5f*t);
  C2 M;
  M.e[0] = make_float2(c, 0.f);  M.e[1] = make_float2(0.f, -s);
  M.e[2] = make_float2(0.f, -s); M.e[3] = make_float2(c, 0.f);
  return M;
}
__device__ C2 gRY(float t) {
  float s = __sinf(0.5f*t), c = __cosf(0.5f*t);
  C2 M;
  M.e[0] = make_float2(c, 0.f);  M.e[1] = make_float2(-s, 0.f);
  M.e[2] = make_float2(s, 0.f);  M.e[3] = make_float2(c, 0.f);
  return M;
}
__device__ C2 gRZ(float t) {
  float s = __sinf(0.5f*t), c = __cosf(0.5f*t);
  C2 M;
  M.e[0] = make_float2(c, -s);    M.e[1] = make_float2(0.f, 0.f);
  M.e[2] = make_float2(0.f, 0.f); M.e[3] = make_float2(c, s);
  return M;
}
__device__ C2 gROT(float phi, float th, float om) {
  return cmm(cmm(gRZ(om), gRY(th)), gRZ(phi));
}

// row-per-thread 2-layer MLP; W1 transposed in LDS, all reads wave-uniform (broadcast).
template<int D>
__device__ __forceinline__ void encode_block(
    const float* __restrict__ x, int r,
    const float* __restrict__ W1, const float* __restrict__ b1,
    const float* __restrict__ W2, const float* __restrict__ b2,
    float* w1t, float* b1s, float* w2s, float* __restrict__ outp, int tid) {
  #pragma unroll
  for (int i = 0; i < D/2; ++i) {
    const int idx = i*256 + tid;
    const float v = W1[idx];
    w1t[(idx & 127)*D + (idx >> 7)] = v;
  }
  if (tid < 128) b1s[tid] = b1[tid];
  w2s[tid] = W2[tid];
  __syncthreads();

  float xv[D];
  *(float4*)xv = *(const float4*)(x + r*D);
  if (D == 8) *(float4*)(xv + 4) = *(const float4*)(x + r*D + 4);

  float o0 = 0.f, o1 = 0.f;
  #pragma unroll 4
  for (int j = 0; j < 128; ++j) {
    float h = b1s[j];
    #pragma unroll
    for (int k = 0; k < D; k += 4) {
      const float4 w = *(const float4*)&w1t[j*D + k];
      h = fmaf(xv[k],   w.x, h);
      h = fmaf(xv[k+1], w.y, h);
      h = fmaf(xv[k+2], w.z, h);
      h = fmaf(xv[k+3], w.w, h);
    }
    h = LEAKY(h);
    const float2 w2 = *(const float2*)&w2s[j*2];
    o0 = fmaf(h, w2.x, o0);
    o1 = fmaf(h, w2.y, o1);
  }
  *(float2*)(outp + r*2) = make_float2(o0 + b2[0], o1 + b2[1]);
}

// blocks 0..135: encoders (256 rows/block, row-per-thread). block 136: gate algebra.
__global__ __launch_bounds__(256) void enc_kernel(
    const float* __restrict__ x_ue, const float* __restrict__ x_ap,
    const float* __restrict__ edge_attr,
    const float* __restrict__ Wn1u, const float* __restrict__ bn1u,
    const float* __restrict__ Wn2u, const float* __restrict__ bn2u,
    const float* __restrict__ Wn1a, const float* __restrict__ bn1a,
    const float* __restrict__ Wn2a, const float* __restrict__ bn2a,
    const float* __restrict__ We1,  const float* __restrict__ be1,
    const float* __restrict__ We2,  const float* __restrict__ be2,
    const float* __restrict__ strongp, const float* __restrict__ initsp,
    const float* __restrict__ updatep, float* __restrict__ ws) {
  __shared__ __align__(16) float w1t[1024];
  __shared__ float b1s[128];
  __shared__ __align__(8) float w2s[256];
  __shared__ float2 U2s[16][17];
  const int bi = blockIdx.x, tid = threadIdx.x;

  if (bi < 32) {
    encode_block<8>(x_ue, bi*256 + tid, Wn1u, bn1u, Wn2u, bn2u,
                    w1t, b1s, w2s, ws + UEE, tid);
    return;
  } else if (bi < 40) {
    encode_block<8>(x_ap, (bi-32)*256 + tid, Wn1a, bn1a, Wn2a, bn2a,
                    w1t, b1s, w2s, ws + APE, tid);
    return;
  } else if (bi < 136) {
    encode_block<4>(edge_attr, (bi-40)*256 + tid, We1, be1, We2, be2,
                    w1t, b1s, w2s, ws + EAE, tid);
    return;
  }

  // ---- gate algebra (block 136) ----
  if (tid < 48) {
    // U_k (k=tid>>4), column col=tid&15. bit masks: wire3=8, nb=4, w7=2, w8=1.
    const int k = tid >> 4, col = tid & 15;
    float2 u[16];
    #pragma unroll
    for (int r = 0; r < 16; ++r) u[r] = make_float2(r == col ? 1.f : 0.f, 0.f);
    #pragma unroll
    for (int l = 0; l < 2; ++l) {
      #pragma unroll
      for (int j = 0; j < 4; ++j) {
        const float* p = updatep + k*24 + l*12 + j*3;
        C2 U = gROT(p[0], p[1], p[2]);
        const int m = 8 >> j;
        #pragma unroll
        for (int r = 0; r < 16; ++r)
          if (!(r & m)) {
            float2 a0 = u[r], a1 = u[r | m];
            u[r]     = cadd(cmul(U.e[0], a0), cmul(U.e[1], a1));
            u[r | m] = cadd(cmul(U.e[2], a0), cmul(U.e[3], a1));
          }
      }
      #pragma unroll
      for (int j = 0; j < 4; ++j) {
        const int mc = 8 >> j;
        const int mt0[4] = {4, 2, 1, 8};
        const int mt1[4] = {2, 1, 8, 4};
        const int mt = (l == 0) ? mt0[j] : mt1[j];
        #pragma unroll
        for (int r = 0; r < 16; ++r)
          if ((r & mc) && !(r & mt)) swap2(u[r], u[r | mt]);
      }
    }
    if (k == 0) {
      if (!(col & 3)) {
        const int jc = col >> 2;
        #pragma unroll
        for (int r = 0; r < 16; ++r) {
          ws[32 + (jc*16 + r)*2 + 0] = u[r].x;
          ws[32 + (jc*16 + r)*2 + 1] = u[r].y;
        }
      }
    } else if (k == 1) {
      // paired layout: U1tp[col][rp] = (U1[r][col], U1[r+4][col]), r = (rp&3)|((rp&4)<<1)
      #pragma unroll
      for (int rp = 0; rp < 8; ++rp) {
        const int r = (rp & 3) | ((rp & 4) << 1);
        ws[160 + (col*8 + rp)*4 + 0] = u[r].x;
        ws[160 + (col*8 + rp)*4 + 1] = u[r].y;
        ws[160 + (col*8 + rp)*4 + 2] = u[r+4].x;
        ws[160 + (col*8 + rp)*4 + 3] = u[r+4].y;
      }
    } else {
      #pragma unroll
      for (int r = 0; r < 16; ++r) U2s[col][r] = u[r];   // U2s[q][t] = U2[t][q]
    }
  }
  if (tid == 48) {
    // M_edge 4x4 (basis (b_e<<1)|b_nb)
    float2 M[4][4];
    #pragma unroll
    for (int r = 0; r < 4; ++r)
      #pragma unroll
      for (int c = 0; c < 4; ++c)
        M[r][c] = make_float2(r == c ? 1.f : 0.f, 0.f);
    auto rowpair = [&](int r0, int r1, C2 U) {
      #pragma unroll
      for (int c = 0; c < 4; ++c) {
        float2 a0 = M[r0][c], a1 = M[r1][c];
        M[r0][c] = cadd(cmul(U.e[0], a0), cmul(U.e[1], a1));
        M[r1][c] = cadd(cmul(U.e[2], a0), cmul(U.e[3], a1));
      }
    };
    auto rowswap = [&](int r0, int r1) {
      #pragma unroll
      for (int c = 0; c < 4; ++c) swap2(M[r0][c], M[r1][c]);
    };
    rowpair(1, 3, gRX(initsp[0]));
    rowpair(2, 3, gRY(initsp[1]));
    #pragma unroll
    for (int l = 0; l < 2; ++l) {
      C2 Re = gROT(strongp[l*6+0], strongp[l*6+1], strongp[l*6+2]);
      C2 Rn = gROT(strongp[l*6+3], strongp[l*6+4], strongp[l*6+5]);
      rowpair(0, 2, Re); rowpair(1, 3, Re);
      rowpair(0, 1, Rn); rowpair(2, 3, Rn);
      rowswap(2, 3);
      rowswap(1, 3);
    }
    #pragma unroll
    for (int r = 0; r < 4; ++r)
      #pragma unroll
      for (int c = 0; c < 4; ++c) {
        ws[(r*4 + c)*2 + 0] = M[r][c].x;
        ws[(r*4 + c)*2 + 1] = M[r][c].y;
      }
  }
  __syncthreads();
  {
    // GP: 256 threads, one (c,cp,n,np) each, 3 wires.
    const int c = tid >> 5, cp = (tid >> 2) & 7, n = (tid >> 1) & 1, np = tid & 1;
    const int q  = ((c  & 4) << 1) | (n  << 2) | (c  & 3);
    const int qp = ((cp & 4) << 1) | (np << 2) | (cp & 3);
    float2 g3 = make_float2(0,0), g7 = g3, g8 = g3;
    #pragma unroll
    for (int t = 0; t < 16; ++t) {
      float2 pr = cmulc(U2s[q][t], U2s[qp][t]);
      g3 = (t & 8) ? csub(g3, pr) : cadd(g3, pr);
      g7 = (t & 2) ? csub(g7, pr) : cadd(g7, pr);
      g8 = (t & 1) ? csub(g8, pr) : cadd(g8, pr);
    }
    const int idx = (c*2 + n)*16 + (cp*2 + np);
    ws[GP_F + (0*256 + idx)*2 + 0] = g3.x;
    ws[GP_F + (0*256 + idx)*2 + 1] = g3.y;
    ws[GP_F + (1*256 + idx)*2 + 0] = g7.x;
    ws[GP_F + (1*256 + idx)*2 + 1] = g7.y;
    ws[GP_F + (2*256 + idx)*2 + 0] = g8.x;
    ws[GP_F + (2*256 + idx)*2 + 1] = g8.y;
  }
}

// 4 UEs/block (1/wave). Consts staged in LDS; enc values read from ws.
__global__ __launch_bounds__(256) void circuit_kernel(
    float* __restrict__ ws, const int* __restrict__ esrc,
    const float* __restrict__ Wu1, const float* __restrict__ bu1,
    const float* __restrict__ Wu2, const float* __restrict__ bu2,
    const float* __restrict__ lng, const float* __restrict__ lnb) {
  __shared__ __align__(16) float2 cst[1104];   // ME 16 | U0c 64 | U1tp 256 | GP 768
  __shared__ __align__(16) float2 pr_s[4][3][4];
  __shared__ __align__(16) float2 psi0[4][2][16];
  __shared__ __align__(16) float4 psi2p[4][8][8];  // [wv][ibr][rp] = (z[r], z[r+4])
  const int tid = threadIdx.x, wv = tid >> 6, lane = tid & 63;
  const int u = blockIdx.x*4 + wv;

  // ---- prefetch per-UE inputs (overlaps staging) ----
  const float2 ue_ab = *(const float2*)(ws + UEE + u*2);
  float2 eab_r = make_float2(0.f, 0.f), nab_r = make_float2(0.f, 0.f);
  if (lane < 12) {
    const int i = lane >> 2;
    eab_r = *(const float2*)(ws + EAE + (u*3 + i)*2);
    const int s = esrc[u*3 + i];
    nab_r = *(const float2*)(ws + APE + s*2);
  }

  {
    const float4* s4 = (const float4*)ws;
    float4* d4 = (float4*)cst;
    #pragma unroll
    for (int i = tid; i < 552; i += 256) d4[i] = s4[i];
  }
  __syncthreads();

  const float2* MEl  = cst;
  const float2* U0cl = cst + 16;
  const float4* U1tp = (const float4*)(cst + 80);   // [q][rp]
  const float4* GP4  = (const float4*)(cst + 336);  // paired GP

  auto mkv = [](float aa, float bb, float2& v0, float2& v1) {
    const float sa = __sinf(0.5f*aa), ca = __cosf(0.5f*aa);
    const float sb = __sinf(0.5f*bb), cb = __cosf(0.5f*bb);
    v0 = make_float2(cb*ca, -sb*ca);
    v1 = make_float2(sa*sb, -sa*cb);
  };
  float2 t0, t1;
  mkv(ue_ab.x, ue_ab.y, t0, t1);

  // ---- pairs (lanes 0..11): i = lane>>2, r = lane&3 ----
  if (lane < 12) {
    const int r = lane & 3;
    float2 e0, e1, n0, n1;
    mkv(eab_r.x, eab_r.y, e0, e1);
    mkv(nab_r.x, nab_r.y, n0, n1);
    float2 in4[4] = {cmul(e0,n0), cmul(e0,n1), cmul(e1,n0), cmul(e1,n1)};
    float2 acc = make_float2(0.f, 0.f);
    #pragma unroll
    for (int cc = 0; cc < 4; ++cc) acc = cadd(acc, cmul(MEl[r*4 + cc], in4[cc]));
    pr_s[wv][lane >> 2][r] = acc;
  }

  // ---- block0: psi0 (lanes 0..31) ----
  if (lane < 32) {
    const int b = lane >> 4, row = lane & 15;
    float2 acc = make_float2(0.f, 0.f);
    #pragma unroll
    for (int j = 0; j < 4; ++j) {
      const float2 phi = pr_s[wv][0][(b << 1) | (j & 1)];
      const float2 coef = cmul((j >> 1) ? t1 : t0, phi);
      acc = cadd(acc, cmul(U0cl[j*16 + row], coef));
    }
    psi0[wv][b][row] = acc;
  }

  // ---- block1: psi2 (all lanes, rows (r, r+4) per lane) ----
  {
    const int ibr = lane >> 3, rp = lane & 7;
    const int db = ibr >> 2, da = (ibr >> 1) & 1, dbp = ibr & 1;
    const float2 f10 = pr_s[wv][1][(dbp << 1) | 0];
    const float2 f11 = pr_s[wv][1][(dbp << 1) | 1];
    float2 chi[8];
    {
      const float4 a0 = *(const float4*)&psi0[wv][db][da*4 + 0];
      const float4 a1 = *(const float4*)&psi0[wv][db][da*4 + 2];
      const float4 a2 = *(const float4*)&psi0[wv][db][8 + da*4 + 0];
      const float4 a3 = *(const float4*)&psi0[wv][db][8 + da*4 + 2];
      chi[0] = make_float2(a0.x, a0.y); chi[1] = make_float2(a0.z, a0.w);
      chi[2] = make_float2(a1.x, a1.y); chi[3] = make_float2(a1.z, a1.w);
      chi[4] = make_float2(a2.x, a2.y); chi[5] = make_float2(a2.z, a2.w);
      chi[6] = make_float2(a3.x, a3.y); chi[7] = make_float2(a3.z, a3.w);
    }
    float2 q0 = make_float2(0.f, 0.f), q1 = q0;
    #pragma unroll
    for (int q = 0; q < 16; ++q) {
      const int cc = ((q >> 3) << 2) | (q & 3);
      const float2 xq = cmul(chi[cc], (q & 4) ? f11 : f10);
      const float4 uf = U1tp[q*8 + rp];
      const float2 u_lo = make_float2(uf.x, uf.y);
      const float2 u_hi = make_float2(uf.z, uf.w);
      q0 = cadd(q0, cmul(u_lo, xq));
      q1 = cadd(q1, cmul(u_hi, xq));
    }
    psi2p[wv][ibr][rp] = make_float4(q0.x, q0.y, q1.x, q1.y);
  }

  // ---- R[c,cp] ----
  const int c = lane >> 3, cp = lane & 7;
  float2 R = make_float2(0.f, 0.f);
  #pragma unroll
  for (int br = 0; br < 8; ++br) {
    const float4 Z1 = psi2p[wv][br][c];
    const float4 Z2 = psi2p[wv][br][cp];
    R.x += Z1.x*Z2.x + Z1.y*Z2.y + Z1.z*Z2.z + Z1.w*Z2.w;
    R.y += Z1.y*Z2.x - Z1.x*Z2.y + Z1.w*Z2.z - Z1.z*Z2.w;
  }

  // ---- rho2, K_w, ev ----
  const float4 f2a = *(const float4*)&pr_s[wv][2][0];
  const float4 f2b = *(const float4*)&pr_s[wv][2][2];
  const float2 f20 = make_float2(f2a.x, f2a.y), f21 = make_float2(f2a.z, f2a.w);
  const float2 f22 = make_float2(f2b.x, f2b.y), f23 = make_float2(f2b.z, f2b.w);
  const float2 rho00 = make_float2(f20.x*f20.x + f20.y*f20.y + f22.x*f22.x + f22.y*f22.y, 0.f);
  const float2 rho11 = make_float2(f21.x*f21.x + f21.y*f21.y + f23.x*f23.x + f23.y*f23.y, 0.f);
  const float2 rho01 = make_float2(fmaf(f20.x,f21.x,f20.y*f21.y) + fmaf(f22.x,f23.x,f22.y*f23.y),
                                   (f20.y*f21.x - f20.x*f21.y) + (f22.y*f23.x - f22.x*f23.y));
  const float2 rho10 = make_float2(rho01.x, -rho01.y);

  float ev0, ev1, ev2;
  {
    const int base4 = c*16 + cp;   // float4 index
    #pragma unroll
    for (int w = 0; w < 3; ++w) {
      const float4 Ga = GP4[w*128 + base4];       // (g00, g01)
      const float4 Gb = GP4[w*128 + base4 + 8];   // (g10, g11)
      const float2 g00 = make_float2(Ga.x, Ga.y), g01 = make_float2(Ga.z, Ga.w);
      const float2 g10 = make_float2(Gb.x, Gb.y), g11 = make_float2(Gb.z, Gb.w);
      float2 K = cmul(g00, rho00);
      K = cadd(K, cmul(g01, rho10));
      K = cadd(K, cmul(g10, rho01));
      K = cadd(K, cmul(g11, rho11));
      const float e = K.x*R.x + K.y*R.y;
      if (w == 0) ev0 = e; else if (w == 1) ev1 = e; else ev2 = e;
    }
  }
  #pragma unroll
  for (int o = 32; o; o >>= 1) {
    ev0 += __shfl_xor(ev0, o);
    ev1 += __shfl_xor(ev1, o);
    ev2 += __shfl_xor(ev2, o);
  }

  // ---- Wu MLP + residual + LN -> g ----
  const int j1 = lane, j2 = lane + 64;
  const float in5[5] = {ue_ab.x, ue_ab.y, ev0, ev1, ev2};
  float h1 = bu1[j1], h2 = bu1[j2];
  #pragma unroll
  for (int k = 0; k < 5; ++k) {
    h1 = fmaf(in5[k], Wu1[k*128 + j1], h1);
    h2 = fmaf(in5[k], Wu1[k*128 + j2], h2);
  }
  h1 = LEAKY(h1); h2 = LEAKY(h2);
  const float2 wu2a = *(const float2*)(Wu2 + j1*2);
  const float2 wu2b = *(const float2*)(Wu2 + j2*2);
  float p0 = fmaf(h1, wu2a.x, h2*wu2b.x);
  float p1 = fmaf(h1, wu2a.y, h2*wu2b.y);
  #pragma unroll
  for (int o = 32; o; o >>= 1) { p0 += __shfl_xor(p0, o); p1 += __shfl_xor(p1, o); }
  if (lane == 0) {
    const float hh0 = ue_ab.x + p0 + bu2[0];
    const float hh1 = ue_ab.y + p1 + bu2[1];
    const float mu = 0.5f*(hh0 + hh1);
    const float dd = hh0 - mu;
    const float inv = rsqrtf(dd*dd + 1e-5f);
    const float g0 =  dd*inv*lng[0] + lnb[0];
    const float g1 = -dd*inv*lng[1] + lnb[1];
    *(float2*)(ws + G_F + u*2) = make_float2(g0, g1);
  }
}

// head GEMM: 64 rows/block, thread tile 4 rows x 8 cols, act transposed in LDS.
__global__ __launch_bounds__(256) void head_kernel(
    const float* __restrict__ g,
    const float* __restrict__ Wf1, const float* __restrict__ bf1,
    const float* __restrict__ Wf2, const float* __restrict__ bf2,
    const float* __restrict__ Wf3, const float* __restrict__ bf3,
    float* __restrict__ out) {
  __shared__ __align__(16) float act_t[128][64];   // [j][row], 32 KB
  const int tid = threadIdx.x;
  const int r0 = blockIdx.x * 64;
  const int wv = tid >> 6;

  // ---- phase 1: act_t[j][row] = leaky(g@Wf1 + bf1), j = p*4 + wv, row = tid&63
  {
    const int row = tid & 63;
    const float2 gv = *(const float2*)(g + (r0 + row)*2);
    #pragma unroll
    for (int p = 0; p < 32; ++p) {
      const int j = p*4 + wv;
      act_t[j][row] = LEAKY(fmaf(gv.x, Wf1[j], fmaf(gv.y, Wf1[128 + j], bf1[j])));
    }
  }
  __syncthreads();

  // ---- phase 2: GEMM. cg = tid&15 (8 cols each), rg = tid>>4 (4 rows each).
  const int cg = tid & 15, rg = tid >> 4;
  float acc[4][8];
  {
    const float4 b0 = *(const float4*)(bf2 + cg*8);
    const float4 b1 = *(const float4*)(bf2 + cg*8 + 4);
    #pragma unroll
    for (int r = 0; r < 4; ++r) {
      acc[r][0]=b0.x; acc[r][1]=b0.y; acc[r][2]=b0.z; acc[r][3]=b0.w;
      acc[r][4]=b1.x; acc[r][5]=b1.y; acc[r][6]=b1.z; acc[r][7]=b1.w;
    }
  }
  #pragma unroll 4
  for (int k = 0; k < 128; ++k) {
    const float4 a4 = *(const float4*)&act_t[k][rg*4];
    const float4 w0 = *(const float4*)(Wf2 + k*128 + cg*8);
    const float4 w1 = *(const float4*)(Wf2 + k*128 + cg*8 + 4);
    const float av[4] = {a4.x, a4.y, a4.z, a4.w};
    #pragma unroll
    for (int r = 0; r < 4; ++r) {
      acc[r][0] = fmaf(av[r], w0.x, acc[r][0]);
      acc[r][1] = fmaf(av[r], w0.y, acc[r][1]);
      acc[r][2] = fmaf(av[r], w0.z, acc[r][2]);
      acc[r][3] = fmaf(av[r], w0.w, acc[r][3]);
      acc[r][4] = fmaf(av[r], w1.x, acc[r][4]);
      acc[r][5] = fmaf(av[r], w1.y, acc[r][5]);
      acc[r][6] = fmaf(av[r], w1.z, acc[r][6]);
      acc[r][7] = fmaf(av[r], w1.w, acc[r][7]);
    }
  }

  // ---- epilogue: leaky, @Wf3, reduce over cg, sigmoid
  float w3x[8], w3y[8];
  #pragma unroll
  for (int c = 0; c < 8; ++c) {
    const float2 w3 = *(const float2*)(Wf3 + (cg*8 + c)*2);
    w3x[c] = w3.x; w3y[c] = w3.y;
  }
  float p0[4], p1[4];
  #pragma unroll
  for (int r = 0; r < 4; ++r) {
    float s0 = 0.f, s1 = 0.f;
    #pragma unroll
    for (int c = 0; c < 8; ++c) {
      const float v = LEAKY(acc[r][c]);
      s0 = fmaf(v, w3x[c], s0);
      s1 = fmaf(v, w3y[c], s1);
    }
    p0[r] = s0; p1[r] = s1;
  }
  #pragma unroll
  for (int o = 8; o; o >>= 1) {
    #pragma unroll
    for (int r = 0; r < 4; ++r) {
      p0[r] += __shfl_xor(p0[r], o);
      p1[r] += __shfl_xor(p1[r], o);
    }
  }
  if (cg == 0) {
    #pragma unroll
    for (int r = 0; r < 4; ++r) {
      const int row = r0 + rg*4 + r;
      const float s0 = 1.f/(1.f + __expf(-(p0[r] + bf3[0])));
      const float s1 = 1.f/(1.f + __expf(-(p1[r] + bf3[1])));
      *(float2*)(out + row*2) = make_float2(s0, s1);
    }
  }
}

extern "C" void kernel_launch(void* const* d_in, const int* in_sizes, int n_in,
                              void* d_out, int out_size, void* d_ws, size_t ws_size,
                              hipStream_t stream) {
  (void)in_sizes; (void)n_in; (void)out_size; (void)ws_size;
  const float* x_ue      = (const float*)d_in[0];
  const float* x_ap      = (const float*)d_in[1];
  const float* edge_attr = (const float*)d_in[2];
  const int*   edge_src  = (const int*)d_in[3];
  const float* Wn1u = (const float*)d_in[5];
  const float* bn1u = (const float*)d_in[6];
  const float* Wn2u = (const float*)d_in[7];
  const float* bn2u = (const float*)d_in[8];
  const float* Wn1a = (const float*)d_in[9];
  const float* bn1a = (const float*)d_in[10];
  const float* Wn2a = (const float*)d_in[11];
  const float* bn2a = (const float*)d_in[12];
  const float* We1  = (const float*)d_in[13];
  const float* be1  = (const float*)d_in[14];
  const float* We2  = (const float*)d_in[15];
  const float* be2  = (const float*)d_in[16];
  const float* strong = (const float*)d_in[17];
  const float* inits  = (const float*)d_in[18];
  const float* update = (const float*)d_in[19];
  const float* Wu1  = (const float*)d_in[20];
  const float* bu1  = (const float*)d_in[21];
  const float* Wu2  = (const float*)d_in[22];
  const float* bu2  = (const float*)d_in[23];
  const float* ln_g = (const float*)d_in[24];
  const float* ln_b = (const float*)d_in[25];
  const float* Wf1  = (const float*)d_in[26];
  const float* bf1  = (const float*)d_in[27];
  const float* Wf2  = (const float*)d_in[28];
  const float* bf2  = (const float*)d_in[29];
  const float* Wf3  = (const float*)d_in[30];
  const float* bf3  = (const float*)d_in[31];

  float* ws = (float*)d_ws;

  enc_kernel<<<137, 256, 0, stream>>>(x_ue, x_ap, edge_attr,
                                      Wn1u, bn1u, Wn2u, bn2u,
                                      Wn1a, bn1a, Wn2a, bn2a,
                                      We1, be1, We2, be2,
                                      strong, inits, update, ws);
  circuit_kernel<<<2048, 256, 0, stream>>>(ws, edge_src,
                                           Wu1, bu1, Wu2, bu2, ln_g, ln_b);
  head_kernel<<<128, 256, 0, stream>>>(ws + G_F, Wf1, bf1, Wf2, bf2, Wf3, bf3,
                                       (float*)d_out);
}

// Round 11
// 37.094 us; speedup vs baseline: 2.0289x; 1.0053x over previous
//
#include <hip/hip_runtime.h>

#define LEAKY(x) ((x) > 0.0f ? (x) : 0.01f * (x))

// ws float layout
#define GP_F    672     // GP inside consts [0..2208)
#define APE     2208    // ap_enc 4096
#define UEE     6304    // ue_enc 16384
#define EAE     22688   // ea_enc 49152
#define G_F     71840   // g 16384

__device__ __forceinline__ float2 cmul(float2 a, float2 b) {
  return make_float2(fmaf(a.x, b.x, -a.y * b.y), fmaf(a.x, b.y, a.y * b.x));
}
__device__ __forceinline__ float2 cmulc(float2 a, float2 b) {  // conj(a)*b
  return make_float2(fmaf(a.x, b.x, a.y * b.y), fmaf(a.x, b.y, -a.y * b.x));
}
__device__ __forceinline__ float2 cadd(float2 a, float2 b) {
  return make_float2(a.x + b.x, a.y + b.y);
}
__device__ __forceinline__ float2 csub(float2 a, float2 b) {
  return make_float2(a.x - b.x, a.y - b.y);
}
__device__ __forceinline__ void swap2(float2& a, float2& b) {
  float2 t = a; a = b; b = t;
}

struct C2 { float2 e[4]; };

__device__ C2 cmm(const C2& A, const C2& B) {
  C2 R;
  #pragma unroll
  for (int r = 0; r < 2; ++r)
    #pragma unroll
    for (int c = 0; c < 2; ++c)
      R.e[r*2+c] = cadd(cmul(A.e[r*2+0], B.e[0*2+c]), cmul(A.e[r*2+1], B.e[1*2+c]));
  return R;
}
__device__ C2 gRX(float t) {
  float s = __sinf(0.5f*t), c = __cosf(0.5f*t);
  C2 M;
  M.e[0] = make_float2(c, 0.f);  M.e[1] = make_float2(0.f, -s);
  M.e[2] = make_float2(0.f, -s); M.e[3] = make_float2(c, 0.f);
  return M;
}
__device__ C2 gRY(float t) {
  float s = __sinf(0.5f*t), c = __cosf(0.5f*t);
  C2 M;
  M.e[0] = make_float2(c, 0.f);  M.e[1] = make_float2(-s, 0.f);
  M.e[2] = make_float2(s, 0.f);  M.e[3] = make_float2(c, 0.f);
  return M;
}
__device__ C2 gRZ(float t) {
  float s = __sinf(0.5f*t), c = __cosf(0.5f*t);
  C2 M;
  M.e[0] = make_float2(c, -s);    M.e[1] = make_float2(0.f, 0.f);
  M.e[2] = make_float2(0.f, 0.f); M.e[3] = make_float2(c, s);
  return M;
}
__device__ C2 gROT(float phi, float th, float om) {
  return cmm(cmm(gRZ(om), gRY(th)), gRZ(phi));
}

// row-per-thread 2-layer MLP; W1 transposed in LDS, all reads wave-uniform (broadcast).
template<int D>
__device__ __forceinline__ void encode_block(
    const float* __restrict__ x, int r,
    const float* __restrict__ W1, const float* __restrict__ b1,
    const float* __restrict__ W2, const float* __restrict__ b2,
    float* w1t, float* b1s, float* w2s, float* __restrict__ outp, int tid) {
  #pragma unroll
  for (int i = 0; i < D/2; ++i) {
    const int idx = i*256 + tid;
    const float v = W1[idx];
    w1t[(idx & 127)*D + (idx >> 7)] = v;
  }
  if (tid < 128) b1s[tid] = b1[tid];
  w2s[tid] = W2[tid];
  __syncthreads();

  float xv[D];
  *(float4*)xv = *(const float4*)(x + r*D);
  if (D == 8) *(float4*)(xv + 4) = *(const float4*)(x + r*D + 4);

  float o0 = 0.f, o1 = 0.f;
  #pragma unroll 4
  for (int j = 0; j < 128; ++j) {
    float h = b1s[j];
    #pragma unroll
    for (int k = 0; k < D; k += 4) {
      const float4 w = *(const float4*)&w1t[j*D + k];
      h = fmaf(xv[k],   w.x, h);
      h = fmaf(xv[k+1], w.y, h);
      h = fmaf(xv[k+2], w.z, h);
      h = fmaf(xv[k+3], w.w, h);
    }
    h = LEAKY(h);
    const float2 w2 = *(const float2*)&w2s[j*2];
    o0 = fmaf(h, w2.x, o0);
    o1 = fmaf(h, w2.y, o1);
  }
  *(float2*)(outp + r*2) = make_float2(o0 + b2[0], o1 + b2[1]);
}

// blocks 0..135: encoders (256 rows/block, row-per-thread). block 136: gate algebra.
__global__ __launch_bounds__(256) void enc_kernel(
    const float* __restrict__ x_ue, const float* __restrict__ x_ap,
    const float* __restrict__ edge_attr,
    const float* __restrict__ Wn1u, const float* __restrict__ bn1u,
    const float* __restrict__ Wn2u, const float* __restrict__ bn2u,
    const float* __restrict__ Wn1a, const float* __restrict__ bn1a,
    const float* __restrict__ Wn2a, const float* __restrict__ bn2a,
    const float* __restrict__ We1,  const float* __restrict__ be1,
    const float* __restrict__ We2,  const float* __restrict__ be2,
    const float* __restrict__ strongp, const float* __restrict__ initsp,
    const float* __restrict__ updatep, float* __restrict__ ws) {
  __shared__ __align__(16) float w1t[1024];
  __shared__ float b1s[128];
  __shared__ __align__(8) float w2s[256];
  __shared__ float2 U2s[16][17];
  const int bi = blockIdx.x, tid = threadIdx.x;

  if (bi < 32) {
    encode_block<8>(x_ue, bi*256 + tid, Wn1u, bn1u, Wn2u, bn2u,
                    w1t, b1s, w2s, ws + UEE, tid);
    return;
  } else if (bi < 40) {
    encode_block<8>(x_ap, (bi-32)*256 + tid, Wn1a, bn1a, Wn2a, bn2a,
                    w1t, b1s, w2s, ws + APE, tid);
    return;
  } else if (bi < 136) {
    encode_block<4>(edge_attr, (bi-40)*256 + tid, We1, be1, We2, be2,
                    w1t, b1s, w2s, ws + EAE, tid);
    return;
  }

  // ---- gate algebra (block 136) ----
  if (tid < 48) {
    // U_k (k=tid>>4), column col=tid&15. bit masks: wire3=8, nb=4, w7=2, w8=1.
    const int k = tid >> 4, col = tid & 15;
    float2 u[16];
    #pragma unroll
    for (int r = 0; r < 16; ++r) u[r] = make_float2(r == col ? 1.f : 0.f, 0.f);
    #pragma unroll
    for (int l = 0; l < 2; ++l) {
      #pragma unroll
      for (int j = 0; j < 4; ++j) {
        const float* p = updatep + k*24 + l*12 + j*3;
        C2 U = gROT(p[0], p[1], p[2]);
        const int m = 8 >> j;
        #pragma unroll
        for (int r = 0; r < 16; ++r)
          if (!(r & m)) {
            float2 a0 = u[r], a1 = u[r | m];
            u[r]     = cadd(cmul(U.e[0], a0), cmul(U.e[1], a1));
            u[r | m] = cadd(cmul(U.e[2], a0), cmul(U.e[3], a1));
          }
      }
      #pragma unroll
      for (int j = 0; j < 4; ++j) {
        const int mc = 8 >> j;
        const int mt0[4] = {4, 2, 1, 8};
        const int mt1[4] = {2, 1, 8, 4};
        const int mt = (l == 0) ? mt0[j] : mt1[j];
        #pragma unroll
        for (int r = 0; r < 16; ++r)
          if ((r & mc) && !(r & mt)) swap2(u[r], u[r | mt]);
      }
    }
    if (k == 0) {
      if (!(col & 3)) {
        const int jc = col >> 2;
        #pragma unroll
        for (int r = 0; r < 16; ++r) {
          ws[32 + (jc*16 + r)*2 + 0] = u[r].x;
          ws[32 + (jc*16 + r)*2 + 1] = u[r].y;
        }
      }
    } else if (k == 1) {
      // paired layout: U1tp[col][rp] = (U1[r][col], U1[r+4][col]), r = (rp&3)|((rp&4)<<1)
      #pragma unroll
      for (int rp = 0; rp < 8; ++rp) {
        const int r = (rp & 3) | ((rp & 4) << 1);
        ws[160 + (col*8 + rp)*4 + 0] = u[r].x;
        ws[160 + (col*8 + rp)*4 + 1] = u[r].y;
        ws[160 + (col*8 + rp)*4 + 2] = u[r+4].x;
        ws[160 + (col*8 + rp)*4 + 3] = u[r+4].y;
      }
    } else {
      #pragma unroll
      for (int r = 0; r < 16; ++r) U2s[col][r] = u[r];   // U2s[q][t] = U2[t][q]
    }
  }
  if (tid == 48) {
    // M_edge 4x4 (basis (b_e<<1)|b_nb)
    float2 M[4][4];
    #pragma unroll
    for (int r = 0; r < 4; ++r)
      #pragma unroll
      for (int c = 0; c < 4; ++c)
        M[r][c] = make_float2(r == c ? 1.f : 0.f, 0.f);
    auto rowpair = [&](int r0, int r1, C2 U) {
      #pragma unroll
      for (int c = 0; c < 4; ++c) {
        float2 a0 = M[r0][c], a1 = M[r1][c];
        M[r0][c] = cadd(cmul(U.e[0], a0), cmul(U.e[1], a1));
        M[r1][c] = cadd(cmul(U.e[2], a0), cmul(U.e[3], a1));
      }
    };
    auto rowswap = [&](int r0, int r1) {
      #pragma unroll
      for (int c = 0; c < 4; ++c) swap2(M[r0][c], M[r1][c]);
    };
    rowpair(1, 3, gRX(initsp[0]));
    rowpair(2, 3, gRY(initsp[1]));
    #pragma unroll
    for (int l = 0; l < 2; ++l) {
      C2 Re = gROT(strongp[l*6+0], strongp[l*6+1], strongp[l*6+2]);
      C2 Rn = gROT(strongp[l*6+3], strongp[l*6+4], strongp[l*6+5]);
      rowpair(0, 2, Re); rowpair(1, 3, Re);
      rowpair(0, 1, Rn); rowpair(2, 3, Rn);
      rowswap(2, 3);
      rowswap(1, 3);
    }
    #pragma unroll
    for (int r = 0; r < 4; ++r)
      #pragma unroll
      for (int c = 0; c < 4; ++c) {
        ws[(r*4 + c)*2 + 0] = M[r][c].x;
        ws[(r*4 + c)*2 + 1] = M[r][c].y;
      }
  }
  __syncthreads();
  {
    // GP: 256 threads, one (c,cp,n,np) each, 3 wires.
    const int c = tid >> 5, cp = (tid >> 2) & 7, n = (tid >> 1) & 1, np = tid & 1;
    const int q  = ((c  & 4) << 1) | (n  << 2) | (c  & 3);
    const int qp = ((cp & 4) << 1) | (np << 2) | (cp & 3);
    float2 g3 = make_float2(0,0), g7 = g3, g8 = g3;
    #pragma unroll
    for (int t = 0; t < 16; ++t) {
      float2 pr = cmulc(U2s[q][t], U2s[qp][t]);
      g3 = (t & 8) ? csub(g3, pr) : cadd(g3, pr);
      g7 = (t & 2) ? csub(g7, pr) : cadd(g7, pr);
      g8 = (t & 1) ? csub(g8, pr) : cadd(g8, pr);
    }
    const int idx = (c*2 + n)*16 + (cp*2 + np);
    ws[GP_F + (0*256 + idx)*2 + 0] = g3.x;
    ws[GP_F + (0*256 + idx)*2 + 1] = g3.y;
    ws[GP_F + (1*256 + idx)*2 + 0] = g7.x;
    ws[GP_F + (1*256 + idx)*2 + 1] = g7.y;
    ws[GP_F + (2*256 + idx)*2 + 0] = g8.x;
    ws[GP_F + (2*256 + idx)*2 + 1] = g8.y;
  }
}

// 4 UEs/block (1/wave). Consts staged in LDS; enc values read from ws.
__global__ __launch_bounds__(256) void circuit_kernel(
    float* __restrict__ ws, const int* __restrict__ esrc,
    const float* __restrict__ Wu1, const float* __restrict__ bu1,
    const float* __restrict__ Wu2, const float* __restrict__ bu2,
    const float* __restrict__ lng, const float* __restrict__ lnb) {
  __shared__ __align__(16) float2 cst[1104];   // ME 16 | U0c 64 | U1tp 256 | GP 768
  __shared__ __align__(16) float2 pr_s[4][3][4];
  __shared__ __align__(16) float2 psi0[4][2][16];
  __shared__ __align__(16) float4 psi2p[4][8][8];  // [wv][ibr][rp] = (z[r], z[r+4])
  const int tid = threadIdx.x, wv = tid >> 6, lane = tid & 63;
  const int u = blockIdx.x*4 + wv;

  // ---- prefetch per-UE inputs (overlaps staging) ----
  const float2 ue_ab = *(const float2*)(ws + UEE + u*2);
  float2 eab_r = make_float2(0.f, 0.f), nab_r = make_float2(0.f, 0.f);
  if (lane < 12) {
    const int i = lane >> 2;
    eab_r = *(const float2*)(ws + EAE + (u*3 + i)*2);
    const int s = esrc[u*3 + i];
    nab_r = *(const float2*)(ws + APE + s*2);
  }

  {
    const float4* s4 = (const float4*)ws;
    float4* d4 = (float4*)cst;
    #pragma unroll
    for (int i = tid; i < 552; i += 256) d4[i] = s4[i];
  }
  __syncthreads();

  const float2* MEl  = cst;
  const float2* U0cl = cst + 16;
  const float4* U1tp = (const float4*)(cst + 80);   // [q][rp]
  const float4* GP4  = (const float4*)(cst + 336);  // paired GP

  auto mkv = [](float aa, float bb, float2& v0, float2& v1) {
    const float sa = __sinf(0.5f*aa), ca = __cosf(0.5f*aa);
    const float sb = __sinf(0.5f*bb), cb = __cosf(0.5f*bb);
    v0 = make_float2(cb*ca, -sb*ca);
    v1 = make_float2(sa*sb, -sa*cb);
  };
  float2 t0, t1;
  mkv(ue_ab.x, ue_ab.y, t0, t1);

  // ---- pairs (lanes 0..11): i = lane>>2, r = lane&3 ----
  if (lane < 12) {
    const int r = lane & 3;
    float2 e0, e1, n0, n1;
    mkv(eab_r.x, eab_r.y, e0, e1);
    mkv(nab_r.x, nab_r.y, n0, n1);
    float2 in4[4] = {cmul(e0,n0), cmul(e0,n1), cmul(e1,n0), cmul(e1,n1)};
    float2 acc = make_float2(0.f, 0.f);
    #pragma unroll
    for (int cc = 0; cc < 4; ++cc) acc = cadd(acc, cmul(MEl[r*4 + cc], in4[cc]));
    pr_s[wv][lane >> 2][r] = acc;
  }

  // ---- block0: psi0 (lanes 0..31) ----
  if (lane < 32) {
    const int b = lane >> 4, row = lane & 15;
    float2 acc = make_float2(0.f, 0.f);
    #pragma unroll
    for (int j = 0; j < 4; ++j) {
      const float2 phi = pr_s[wv][0][(b << 1) | (j & 1)];
      const float2 coef = cmul((j >> 1) ? t1 : t0, phi);
      acc = cadd(acc, cmul(U0cl[j*16 + row], coef));
    }
    psi0[wv][b][row] = acc;
  }

  // ---- block1: psi2 (all lanes, rows (r, r+4) per lane) ----
  {
    const int ibr = lane >> 3, rp = lane & 7;
    const int db = ibr >> 2, da = (ibr >> 1) & 1, dbp = ibr & 1;
    const float2 f10 = pr_s[wv][1][(dbp << 1) | 0];
    const float2 f11 = pr_s[wv][1][(dbp << 1) | 1];
    float2 chi[8];
    {
      const float4 a0 = *(const float4*)&psi0[wv][db][da*4 + 0];
      const float4 a1 = *(const float4*)&psi0[wv][db][da*4 + 2];
      const float4 a2 = *(const float4*)&psi0[wv][db][8 + da*4 + 0];
      const float4 a3 = *(const float4*)&psi0[wv][db][8 + da*4 + 2];
      chi[0] = make_float2(a0.x, a0.y); chi[1] = make_float2(a0.z, a0.w);
      chi[2] = make_float2(a1.x, a1.y); chi[3] = make_float2(a1.z, a1.w);
      chi[4] = make_float2(a2.x, a2.y); chi[5] = make_float2(a2.z, a2.w);
      chi[6] = make_float2(a3.x, a3.y); chi[7] = make_float2(a3.z, a3.w);
    }
    float2 q0 = make_float2(0.f, 0.f), q1 = q0;
    #pragma unroll
    for (int q = 0; q < 16; ++q) {
      const int cc = ((q >> 3) << 2) | (q & 3);
      const float2 xq = cmul(chi[cc], (q & 4) ? f11 : f10);
      const float4 uf = U1tp[q*8 + rp];
      const float2 u_lo = make_float2(uf.x, uf.y);
      const float2 u_hi = make_float2(uf.z, uf.w);
      q0 = cadd(q0, cmul(u_lo, xq));
      q1 = cadd(q1, cmul(u_hi, xq));
    }
    psi2p[wv][ibr][rp] = make_float4(q0.x, q0.y, q1.x, q1.y);
  }

  // ---- R[c,cp] ----
  const int c = lane >> 3, cp = lane & 7;
  float2 R = make_float2(0.f, 0.f);
  #pragma unroll
  for (int br = 0; br < 8; ++br) {
    const float4 Z1 = psi2p[wv][br][c];
    const float4 Z2 = psi2p[wv][br][cp];
    R.x += Z1.x*Z2.x + Z1.y*Z2.y + Z1.z*Z2.z + Z1.w*Z2.w;
    R.y += Z1.y*Z2.x - Z1.x*Z2.y + Z1.w*Z2.z - Z1.z*Z2.w;
  }

  // ---- rho2, K_w, ev ----
  const float4 f2a = *(const float4*)&pr_s[wv][2][0];
  const float4 f2b = *(const float4*)&pr_s[wv][2][2];
  const float2 f20 = make_float2(f2a.x, f2a.y), f21 = make_float2(f2a.z, f2a.w);
  const float2 f22 = make_float2(f2b.x, f2b.y), f23 = make_float2(f2b.z, f2b.w);
  const float2 rho00 = make_float2(f20.x*f20.x + f20.y*f20.y + f22.x*f22.x + f22.y*f22.y, 0.f);
  const float2 rho11 = make_float2(f21.x*f21.x + f21.y*f21.y + f23.x*f23.x + f23.y*f23.y, 0.f);
  const float2 rho01 = make_float2(fmaf(f20.x,f21.x,f20.y*f21.y) + fmaf(f22.x,f23.x,f22.y*f23.y),
                                   (f20.y*f21.x - f20.x*f21.y) + (f22.y*f23.x - f22.x*f23.y));
  const float2 rho10 = make_float2(rho01.x, -rho01.y);

  float ev0, ev1, ev2;
  {
    const int base4 = c*16 + cp;   // float4 index
    #pragma unroll
    for (int w = 0; w < 3; ++w) {
      const float4 Ga = GP4[w*128 + base4];       // (g00, g01)
      const float4 Gb = GP4[w*128 + base4 + 8];   // (g10, g11)
      const float2 g00 = make_float2(Ga.x, Ga.y), g01 = make_float2(Ga.z, Ga.w);
      const float2 g10 = make_float2(Gb.x, Gb.y), g11 = make_float2(Gb.z, Gb.w);
      float2 K = cmul(g00, rho00);
      K = cadd(K, cmul(g01, rho10));
      K = cadd(K, cmul(g10, rho01));
      K = cadd(K, cmul(g11, rho11));
      const float e = K.x*R.x + K.y*R.y;
      if (w == 0) ev0 = e; else if (w == 1) ev1 = e; else ev2 = e;
    }
  }
  #pragma unroll
  for (int o = 32; o; o >>= 1) {
    ev0 += __shfl_xor(ev0, o);
    ev1 += __shfl_xor(ev1, o);
    ev2 += __shfl_xor(ev2, o);
  }

  // ---- Wu MLP + residual + LN -> g ----
  const int j1 = lane, j2 = lane + 64;
  const float in5[5] = {ue_ab.x, ue_ab.y, ev0, ev1, ev2};
  float h1 = bu1[j1], h2 = bu1[j2];
  #pragma unroll
  for (int k = 0; k < 5; ++k) {
    h1 = fmaf(in5[k], Wu1[k*128 + j1], h1);
    h2 = fmaf(in5[k], Wu1[k*128 + j2], h2);
  }
  h1 = LEAKY(h1); h2 = LEAKY(h2);
  const float2 wu2a = *(const float2*)(Wu2 + j1*2);
  const float2 wu2b = *(const float2*)(Wu2 + j2*2);
  float p0 = fmaf(h1, wu2a.x, h2*wu2b.x);
  float p1 = fmaf(h1, wu2a.y, h2*wu2b.y);
  #pragma unroll
  for (int o = 32; o; o >>= 1) { p0 += __shfl_xor(p0, o); p1 += __shfl_xor(p1, o); }
  if (lane == 0) {
    const float hh0 = ue_ab.x + p0 + bu2[0];
    const float hh1 = ue_ab.y + p1 + bu2[1];
    const float mu = 0.5f*(hh0 + hh1);
    const float dd = hh0 - mu;
    const float inv = rsqrtf(dd*dd + 1e-5f);
    const float g0 =  dd*inv*lng[0] + lnb[0];
    const float g1 = -dd*inv*lng[1] + lnb[1];
    *(float2*)(ws + G_F + u*2) = make_float2(g0, g1);
  }
}

// head GEMM: 64 rows/block, thread tile 4 rows x 8 cols, act transposed in LDS.
__global__ __launch_bounds__(256) void head_kernel(
    const float* __restrict__ g,
    const float* __restrict__ Wf1, const float* __restrict__ bf1,
    const float* __restrict__ Wf2, const float* __restrict__ bf2,
    const float* __restrict__ Wf3, const float* __restrict__ bf3,
    float* __restrict__ out) {
  __shared__ __align__(16) float act_t[128][64];   // [j][row], 32 KB
  const int tid = threadIdx.x;
  const int r0 = blockIdx.x * 64;
  const int wv = tid >> 6;

  // ---- phase 1: act_t[j][row] = leaky(g@Wf1 + bf1), j = p*4 + wv, row = tid&63
  {
    const int row = tid & 63;
    const float2 gv = *(const float2*)(g + (r0 + row)*2);
    #pragma unroll
    for (int p = 0; p < 32; ++p) {
      const int j = p*4 + wv;
      act_t[j][row] = LEAKY(fmaf(gv.x, Wf1[j], fmaf(gv.y, Wf1[128 + j], bf1[j])));
    }
  }
  __syncthreads();

  // ---- phase 2: GEMM. cg = tid&15 (8 cols each), rg = tid>>4 (4 rows each).
  const int cg = tid & 15, rg = tid >> 4;
  float acc[4][8];
  {
    const float4 b0 = *(const float4*)(bf2 + cg*8);
    const float4 b1 = *(const float4*)(bf2 + cg*8 + 4);
    #pragma unroll
    for (int r = 0; r < 4; ++r) {
      acc[r][0]=b0.x; acc[r][1]=b0.y; acc[r][2]=b0.z; acc[r][3]=b0.w;
      acc[r][4]=b1.x; acc[r][5]=b1.y; acc[r][6]=b1.z; acc[r][7]=b1.w;
    }
  }
  #pragma unroll 4
  for (int k = 0; k < 128; ++k) {
    const float4 a4 = *(const float4*)&act_t[k][rg*4];
    const float4 w0 = *(const float4*)(Wf2 + k*128 + cg*8);
    const float4 w1 = *(const float4*)(Wf2 + k*128 + cg*8 + 4);
    const float av[4] = {a4.x, a4.y, a4.z, a4.w};
    #pragma unroll
    for (int r = 0; r < 4; ++r) {
      acc[r][0] = fmaf(av[r], w0.x, acc[r][0]);
      acc[r][1] = fmaf(av[r], w0.y, acc[r][1]);
      acc[r][2] = fmaf(av[r], w0.z, acc[r][2]);
      acc[r][3] = fmaf(av[r], w0.w, acc[r][3]);
      acc[r][4] = fmaf(av[r], w1.x, acc[r][4]);
      acc[r][5] = fmaf(av[r], w1.y, acc[r][5]);
      acc[r][6] = fmaf(av[r], w1.z, acc[r][6]);
      acc[r][7] = fmaf(av[r], w1.w, acc[r][7]);
    }
  }

  // ---- epilogue: leaky, @Wf3, reduce over cg, sigmoid
  float w3x[8], w3y[8];
  #pragma unroll
  for (int c = 0; c < 8; ++c) {
    const float2 w3 = *(const float2*)(Wf3 + (cg*8 + c)*2);
    w3x[c] = w3.x; w3y[c] = w3.y;
  }
  float p0[4], p1[4];
  #pragma unroll
  for (int r = 0; r < 4; ++r) {
    float s0 = 0.f, s1 = 0.f;
    #pragma unroll
    for (int c = 0; c < 8; ++c) {
      const float v = LEAKY(acc[r][c]);
      s0 = fmaf(v, w3x[c], s0);
      s1 = fmaf(v, w3y[c], s1);
    }
    p0[r] = s0; p1[r] = s1;
  }
  #pragma unroll
  for (int o = 8; o; o >>= 1) {
    #pragma unroll
    for (int r = 0; r < 4; ++r) {
      p0[r] += __shfl_xor(p0[r], o);
      p1[r] += __shfl_xor(p1[r], o);
    }
  }
  if (cg == 0) {
    #pragma unroll
    for (int r = 0; r < 4; ++r) {
      const int row = r0 + rg*4 + r;
      const float s0 = 1.f/(1.f + __expf(-(p0[r] + bf3[0])));
      const float s1 = 1.f/(1.f + __expf(-(p1[r] + bf3[1])));
      *(float2*)(out + row*2) = make_float2(s0, s1);
    }
  }
}

extern "C" void kernel_launch(void* const* d_in, const int* in_sizes, int n_in,
                              void* d_out, int out_size, void* d_ws, size_t ws_size,
                              hipStream_t stream) {
  (void)in_sizes; (void)n_in; (void)out_size; (void)ws_size;
  const float* x_ue      = (const float*)d_in[0];
  const float* x_ap      = (const float*)d_in[1];
  const float* edge_attr = (const float*)d_in[2];
  const int*   edge_src  = (const int*)d_in[3];
  const float* Wn1u = (const float*)d_in[5];
  const float* bn1u = (const float*)d_in[6];
  const float* Wn2u = (const float*)d_in[7];
  const float* bn2u = (const float*)d_in[8];
  const float* Wn1a = (const float*)d_in[9];
  const float* bn1a = (const float*)d_in[10];
  const float* Wn2a = (const float*)d_in[11];
  const float* bn2a = (const float*)d_in[12];
  const float* We1  = (const float*)d_in[13];
  const float* be1  = (const float*)d_in[14];
  const float* We2  = (const float*)d_in[15];
  const float* be2  = (const float*)d_in[16];
  const float* strong = (const float*)d_in[17];
  const float* inits  = (const float*)d_in[18];
  const float* update = (const float*)d_in[19];
  const float* Wu1  = (const float*)d_in[20];
  const float* bu1  = (const float*)d_in[21];
  const float* Wu2  = (const float*)d_in[22];
  const float* bu2  = (const float*)d_in[23];
  const float* ln_g = (const float*)d_in[24];
  const float* ln_b = (const float*)d_in[25];
  const float* Wf1  = (const float*)d_in[26];
  const float* bf1  = (const float*)d_in[27];
  const float* Wf2  = (const float*)d_in[28];
  const float* bf2  = (const float*)d_in[29];
  const float* Wf3  = (const float*)d_in[30];
  const float* bf3  = (const float*)d_in[31];

  float* ws = (float*)d_ws;

  enc_kernel<<<137, 256, 0, stream>>>(x_ue, x_ap, edge_attr,
                                      Wn1u, bn1u, Wn2u, bn2u,
                                      Wn1a, bn1a, Wn2a, bn2a,
                                      We1, be1, We2, be2,
                                      strong, inits, update, ws);
  circuit_kernel<<<2048, 256, 0, stream>>>(ws, edge_src,
                                           Wu1, bu1, Wu2, bu2, ln_g, ln_b);
  head_kernel<<<128, 256, 0, stream>>>(ws + G_F, Wf1, bf1, Wf2, bf2, Wf3, bf3,
                                       (float*)d_out);
}